// Round 4
// baseline (1520.760 us; speedup 1.0000x reference)
//
#include <hip/hip_runtime.h>
#include <stdint.h>

typedef unsigned short u16;
typedef short short8 __attribute__((ext_vector_type(8)));
typedef float f32x4 __attribute__((ext_vector_type(4)));
typedef u16 u16x4 __attribute__((ext_vector_type(4)));

#define MODE_F32  0
#define MODE_GELU 2
#define MODE_VT   4

__device__ __forceinline__ float b2f(u16 v) {
    union { uint32_t u; float f; } x; x.u = ((uint32_t)v) << 16; return x.f;
}
__device__ __forceinline__ u16 f2b(float f) {
    union { float f; uint32_t u; } x; x.f = f;
    uint32_t u = x.u;
    return (u16)((u + 0x7FFFu + ((u >> 16) & 1u)) >> 16);   // RNE
}

// async global->LDS, 16B per lane; LDS dest is wave-uniform base + lane*16
#define ASYNC16(gp, lp)                                                        \
    __builtin_amdgcn_global_load_lds(                                          \
        (const __attribute__((address_space(1))) uint32_t*)(const void*)(gp),  \
        (__attribute__((address_space(3))) uint32_t*)(void*)(lp), 16, 0, 0)

#define MFMA16(a, b, c) __builtin_amdgcn_mfma_f32_16x16x32_bf16((a), (b), (c), 0, 0, 0)

// ---------------------------------------------------------------------------
// fp32 -> (hi, lo) bf16 split:  x ~= b2f(hi) + b2f(lo), error ~2^-18 rel
// ---------------------------------------------------------------------------
__global__ __launch_bounds__(256) void split_f32(
    const float* __restrict__ in, u16* __restrict__ hi, u16* __restrict__ lo)
{
    const int i = (blockIdx.x * 256 + threadIdx.x) * 4;
    f32x4 v = *(const f32x4*)&in[i];
    u16x4 h, l;
    for (int k = 0; k < 4; k++) {
        h[k] = f2b(v[k]);
        l[k] = f2b(v[k] - b2f(h[k]));
    }
    *(u16x4*)&hi[i] = h;
    *(u16x4*)&lo[i] = l;
}

// fp32 [rows,cols] -> bf16 [cols,rows] transpose+cast (single)
__global__ __launch_bounds__(256) void transpose_f32_bf16(
    const float* __restrict__ in, u16* __restrict__ out, int rows, int cols)
{
    __shared__ float t[32][33];
    const int r0 = blockIdx.y * 32, c0 = blockIdx.x * 32;
    const int tr = threadIdx.x >> 3, tc = (threadIdx.x & 7) * 4;
    f32x4 v = *(const f32x4*)&in[(size_t)(r0 + tr) * cols + c0 + tc];
    for (int i = 0; i < 4; i++) t[tr][tc + i] = v[i];
    __syncthreads();
    u16x4 ov;
    for (int i = 0; i < 4; i++) ov[i] = f2b(t[tc + i][tr]);
    *(u16x4*)&out[(size_t)(c0 + tr) * rows + r0 + tc] = ov;
}

// fp32 [rows,cols] -> bf16 hi/lo [cols,rows] transpose+split
__global__ __launch_bounds__(256) void transpose_split_f32(
    const float* __restrict__ in, u16* __restrict__ hi, u16* __restrict__ lo,
    int rows, int cols)
{
    __shared__ float t[32][33];
    const int r0 = blockIdx.y * 32, c0 = blockIdx.x * 32;
    const int tr = threadIdx.x >> 3, tc = (threadIdx.x & 7) * 4;
    f32x4 v = *(const f32x4*)&in[(size_t)(r0 + tr) * cols + c0 + tc];
    for (int i = 0; i < 4; i++) t[tr][tc + i] = v[i];
    __syncthreads();
    u16x4 hv, lv;
    for (int i = 0; i < 4; i++) {
        const float f = t[tc + i][tr];
        hv[i] = f2b(f);
        lv[i] = f2b(f - b2f(hv[i]));
    }
    const size_t o = (size_t)(c0 + tr) * rows + r0 + tc;
    *(u16x4*)&hi[o] = hv;
    *(u16x4*)&lo[o] = lv;
}

// ---------------------------------------------------------------------------
// QK projection, bf16x3: C = (Ahi+Alo)(Bhi+Blo)^T + bias (lo*lo dropped)
// M=4096, N=2048 (Q cols 0..1023, K cols 1024..2047), K=1024
// Outputs Q,K as hi/lo bf16 pairs for the precision-critical QK^T.
// ---------------------------------------------------------------------------
__global__ __launch_bounds__(256) void gemm_qk_x3(
    const u16* __restrict__ Ahi, const u16* __restrict__ Alo,
    const u16* __restrict__ Bhi, const u16* __restrict__ Blo,
    const float* __restrict__ bq, const float* __restrict__ bk,
    u16* __restrict__ Qhi, u16* __restrict__ Qlo,
    u16* __restrict__ Khi, u16* __restrict__ Klo)
{
    const int K = 1024;
    __shared__ u16 lAh[128 * 32], lAl[128 * 32];
    __shared__ u16 lBh[128 * 32], lBl[128 * 32];

    const int tid = threadIdx.x;
    const int w = tid >> 6, lane = tid & 63;
    const int lane15 = lane & 15, q = lane >> 4;
    const int tM = blockIdx.y * 128, tN = blockIdx.x * 128;
    const int m0 = (w >> 1) * 64, n0 = (w & 1) * 64;

    f32x4 acc[4][4];
    for (int i = 0; i < 4; i++)
        for (int j = 0; j < 4; j++)
            acc[i][j] = (f32x4){0.f, 0.f, 0.f, 0.f};

    const int pa0 = 2 * w, pa1 = 2 * w + 1;
    const int srow = lane >> 2, sch = lane & 3;
    const u16* Ah = Ahi + (size_t)tM * K;
    const u16* Al = Alo + (size_t)tM * K;
    const u16* Bh = Bhi + (size_t)tN * K;
    const u16* Bl = Blo + (size_t)tN * K;

    for (int k0 = 0; k0 < K; k0 += 32) {
        const size_t o0 = (size_t)(pa0 * 16 + srow) * K + k0 + sch * 8;
        const size_t o1 = (size_t)(pa1 * 16 + srow) * K + k0 + sch * 8;
        ASYNC16(Ah + o0, &lAh[pa0 * 512]);  ASYNC16(Ah + o1, &lAh[pa1 * 512]);
        ASYNC16(Al + o0, &lAl[pa0 * 512]);  ASYNC16(Al + o1, &lAl[pa1 * 512]);
        ASYNC16(Bh + o0, &lBh[pa0 * 512]);  ASYNC16(Bh + o1, &lBh[pa1 * 512]);
        ASYNC16(Bl + o0, &lBl[pa0 * 512]);  ASYNC16(Bl + o1, &lBl[pa1 * 512]);
        __syncthreads();
        short8 afh[4], afl[4], bfh[4], bfl[4];
        for (int i = 0; i < 4; i++) {
            const int o = (m0 + i * 16 + lane15) * 32 + q * 8;
            afh[i] = *(const short8*)&lAh[o];
            afl[i] = *(const short8*)&lAl[o];
        }
        for (int j = 0; j < 4; j++) {
            const int o = (n0 + j * 16 + lane15) * 32 + q * 8;
            bfh[j] = *(const short8*)&lBh[o];
            bfl[j] = *(const short8*)&lBl[o];
        }
        __syncthreads();
        for (int i = 0; i < 4; i++)
            for (int j = 0; j < 4; j++) {
                acc[i][j] = MFMA16(afh[i], bfh[j], acc[i][j]);
                acc[i][j] = MFMA16(afh[i], bfl[j], acc[i][j]);
                acc[i][j] = MFMA16(afl[i], bfh[j], acc[i][j]);
            }
    }

    for (int i = 0; i < 4; i++) {
        const int rb = tM + m0 + i * 16 + q * 4;
        for (int j = 0; j < 4; j++) {
            const int col = tN + n0 + j * 16 + lane15;
            const float bv = (col < 1024) ? bq[col] : bk[col - 1024];
            for (int r = 0; r < 4; r++) {
                const int row = rb + r;
                const float v = acc[i][j][r] + bv;
                const u16 hv = f2b(v);
                const u16 lv = f2b(v - b2f(hv));
                if (col < 1024) {
                    Qhi[(size_t)row * 1024 + col] = hv;
                    Qlo[(size_t)row * 1024 + col] = lv;
                } else {
                    Khi[(size_t)row * 1024 + col - 1024] = hv;
                    Klo[(size_t)row * 1024 + col - 1024] = lv;
                }
            }
        }
    }
}

// ---------------------------------------------------------------------------
// C = A[M,K] * Bt[N,K]^T + bias; bf16 in; m97-style 128x128xBK32
// modes: F32 out, GELU->bf16 out, VT (V-transpose scatter, N=1024)
// ---------------------------------------------------------------------------
__global__ __launch_bounds__(256) void gemm_bt(
    const u16* __restrict__ A, const u16* __restrict__ Bt, const float* __restrict__ bias,
    int M, int N, int K, int mode,
    float* __restrict__ outF, u16* __restrict__ outB)
{
    __shared__ u16 lA[128 * 32];
    __shared__ u16 lB[128 * 32];

    const int tid = threadIdx.x;
    const int w = tid >> 6, lane = tid & 63;
    const int lane15 = lane & 15, q = lane >> 4;
    const int tM = blockIdx.y * 128, tN = blockIdx.x * 128;
    const int m0 = (w >> 1) * 64, n0 = (w & 1) * 64;

    f32x4 acc[4][4];
    for (int i = 0; i < 4; i++)
        for (int j = 0; j < 4; j++)
            acc[i][j] = (f32x4){0.f, 0.f, 0.f, 0.f};

    const int pa0 = 2 * w, pa1 = 2 * w + 1;
    const int srow = lane >> 2, sch = lane & 3;
    const u16* Abase = A + (size_t)tM * K;
    const u16* Bbase = Bt + (size_t)tN * K;

    for (int k0 = 0; k0 < K; k0 += 32) {
        ASYNC16(Abase + (size_t)(pa0 * 16 + srow) * K + k0 + sch * 8, &lA[pa0 * 512]);
        ASYNC16(Abase + (size_t)(pa1 * 16 + srow) * K + k0 + sch * 8, &lA[pa1 * 512]);
        ASYNC16(Bbase + (size_t)(pa0 * 16 + srow) * K + k0 + sch * 8, &lB[pa0 * 512]);
        ASYNC16(Bbase + (size_t)(pa1 * 16 + srow) * K + k0 + sch * 8, &lB[pa1 * 512]);
        __syncthreads();
        short8 af[4], bf[4];
        for (int i = 0; i < 4; i++) af[i] = *(const short8*)&lA[(m0 + i * 16 + lane15) * 32 + q * 8];
        for (int j = 0; j < 4; j++) bf[j] = *(const short8*)&lB[(n0 + j * 16 + lane15) * 32 + q * 8];
        __syncthreads();
        for (int i = 0; i < 4; i++)
            for (int j = 0; j < 4; j++)
                acc[i][j] = MFMA16(af[i], bf[j], acc[i][j]);
    }

    for (int i = 0; i < 4; i++) {
        const int rb = tM + m0 + i * 16 + q * 4;
        for (int j = 0; j < 4; j++) {
            const int col = tN + n0 + j * 16 + lane15;
            const float bv = bias ? bias[col] : 0.f;
            for (int r = 0; r < 4; r++) {
                const int row = rb + r;
                float v = acc[i][j][r] + bv;
                if (mode == MODE_F32) {
                    outF[(size_t)row * N + col] = v;
                } else if (mode == MODE_GELU) {
                    v = 0.5f * v * (1.f + erff(v * 0.70710678118f));
                    outB[(size_t)row * N + col] = f2b(v);
                } else {  // MODE_VT: V^T per (b,h): out[((b*16+h)*64+d)*2048 + n]
                    const int bb = row >> 11, n = row & 2047;
                    outB[((size_t)(bb * 16 + (col >> 6)) * 64 + (col & 63)) * 2048 + n] = f2b(v);
                }
            }
        }
    }
}

// ---------------------------------------------------------------------------
// Flash attention with bf16x3 QK^T: scores = (Q K^T) * 8.0, causal, softmax, PV
// Qhi/Qlo,Khi/Klo: [b*2048+n][1024]; Vt: [(b*16+h)*64+d][2048]
// grid 512 = 32 (b,h) x 16 pairs; WG does q-blocks {pair, 31-pair} of 64 rows
// ---------------------------------------------------------------------------
__global__ __launch_bounds__(256) void attn_fwd(
    const u16* __restrict__ Qhig, const u16* __restrict__ Qlog,
    const u16* __restrict__ Khig, const u16* __restrict__ Klog,
    const u16* __restrict__ Vtg, u16* __restrict__ Og)
{
    __shared__ u16 lQh[2][2048], lQl[2][2048];   // [d-half][row*32]
    __shared__ u16 lKh[2][1024], lKl[2][1024];   // [d-half][key*32]
    __shared__ u16 lV[2048];                     // [d][key]
    __shared__ u16 lP[4][640];                   // per-wave P, stride 40

    const int tid = threadIdx.x, w = tid >> 6, lane = tid & 63;
    const int lane15 = lane & 15, q = lane >> 4;
    const int bh = blockIdx.x >> 4, pair = blockIdx.x & 15;
    const int b = bh >> 4, h = bh & 15;

    const size_t xoff = (size_t)b * 2048 * 1024 + h * 64;
    const u16* Qh_ = Qhig + xoff;
    const u16* Ql_ = Qlog + xoff;
    const u16* Kh_ = Khig + xoff;
    const u16* Kl_ = Klog + xoff;
    const u16* Vbh = Vtg + (size_t)bh * 64 * 2048;
    u16* Obh = Og + xoff;

    const int srow = lane >> 2, sch = lane & 3;
    const float NEG = -3.0e38f;

    for (int half = 0; half < 2; half++) {
        const int qb = half ? (31 - pair) : pair;
        const int qrow0 = qb * 64;
        const int ntiles = 2 * qb + 2;

        // stage Q hi+lo (16 chunks, 4 per wave)
        for (int ii = 0; ii < 4; ii++) {
            const int id = w * 4 + ii;
            const int idq = id & 7, ks = idq >> 2, p = idq & 3;
            const size_t so = (size_t)(qrow0 + p * 16 + srow) * 1024 + ks * 32 + sch * 8;
            if (id < 8) ASYNC16(Qh_ + so, &lQh[ks][p * 512]);
            else        ASYNC16(Ql_ + so, &lQl[ks][p * 512]);
        }

        f32x4 o[4];
        for (int j = 0; j < 4; j++) o[j] = (f32x4){0.f, 0.f, 0.f, 0.f};
        float mrow[4], lrow[4];
        for (int r = 0; r < 4; r++) { mrow[r] = NEG; lrow[r] = 0.f; }
        short8 aqh0 = {}, aqh1 = {}, aql0 = {}, aql1 = {};
        bool first = true;

        for (int t = 0; t < ntiles; t++) {
            const int kk0 = t * 32;
            // stage K hi+lo (8 chunks) and Vt (4 chunks): 3 per wave
            for (int ii = 0; ii < 3; ii++) {
                const int id = w * 3 + ii;
                if (id < 8) {
                    const int sel = id >> 2, idk = id & 3, ks = idk >> 1, hh = idk & 1;
                    const size_t so = (size_t)(kk0 + hh * 16 + srow) * 1024 + ks * 32 + sch * 8;
                    if (sel == 0) ASYNC16(Kh_ + so, &lKh[ks][hh * 512]);
                    else          ASYNC16(Kl_ + so, &lKl[ks][hh * 512]);
                } else {
                    const int p = id - 8;
                    ASYNC16(Vbh + (size_t)(p * 16 + srow) * 2048 + kk0 + sch * 8, &lV[p * 512]);
                }
            }
            __syncthreads();
            if (first) {
                const int o0 = (w * 16 + lane15) * 32 + q * 8;
                aqh0 = *(const short8*)&lQh[0][o0];
                aqh1 = *(const short8*)&lQh[1][o0];
                aql0 = *(const short8*)&lQl[0][o0];
                aql1 = *(const short8*)&lQl[1][o0];
                first = false;
            }
            // S = (Qhi+Qlo)(Khi+Klo)^T, lo*lo dropped
            f32x4 s[2];
            for (int sub = 0; sub < 2; sub++) {
                const int ko = (sub * 16 + lane15) * 32 + q * 8;
                short8 bkh0 = *(const short8*)&lKh[0][ko];
                short8 bkh1 = *(const short8*)&lKh[1][ko];
                short8 bkl0 = *(const short8*)&lKl[0][ko];
                short8 bkl1 = *(const short8*)&lKl[1][ko];
                f32x4 z = (f32x4){0.f, 0.f, 0.f, 0.f};
                z = MFMA16(aqh0, bkh0, z);
                z = MFMA16(aqh1, bkh1, z);
                z = MFMA16(aqh0, bkl0, z);
                z = MFMA16(aqh1, bkl1, z);
                z = MFMA16(aql0, bkh0, z);
                z = MFMA16(aql1, bkh1, z);
                s[sub] = z;
            }
            // scale (bug-faithful *8) + causal mask
            const int rbase = qrow0 + w * 16 + q * 4;
            for (int sub = 0; sub < 2; sub++)
                for (int r = 0; r < 4; r++) {
                    const int key = kk0 + sub * 16 + lane15;
                    float sv = s[sub][r] * 8.0f;
                    if (key > rbase + r) sv = NEG;
                    s[sub][r] = sv;
                }
            // online softmax (rows in 16-lane groups)
            float mx[4];
            for (int r = 0; r < 4; r++) mx[r] = fmaxf(s[0][r], s[1][r]);
            for (int d = 1; d < 16; d <<= 1)
                for (int r = 0; r < 4; r++) mx[r] = fmaxf(mx[r], __shfl_xor(mx[r], d));
            float alpha[4];
            for (int r = 0; r < 4; r++) {
                const float mnew = fmaxf(mrow[r], mx[r]);
                alpha[r] = __expf(mrow[r] - mnew);
                mrow[r] = mnew;
            }
            float rsum[4] = {0.f, 0.f, 0.f, 0.f};
            for (int sub = 0; sub < 2; sub++)
                for (int r = 0; r < 4; r++) {
                    const float p = __expf(s[sub][r] - mrow[r]);
                    rsum[r] += p;
                    lP[w][(q * 4 + r) * 40 + sub * 16 + lane15] = f2b(p);
                }
            for (int d = 1; d < 16; d <<= 1)
                for (int r = 0; r < 4; r++) rsum[r] += __shfl_xor(rsum[r], d);
            for (int r = 0; r < 4; r++) lrow[r] = lrow[r] * alpha[r] + rsum[r];
            for (int j = 0; j < 4; j++)
                for (int r = 0; r < 4; r++) o[j][r] *= alpha[r];
            // O += P V
            short8 ap = *(const short8*)&lP[w][lane15 * 40 + q * 8];
            for (int j = 0; j < 4; j++) {
                short8 bv = *(const short8*)&lV[(j * 16 + lane15) * 32 + q * 8];
                o[j] = MFMA16(ap, bv, o[j]);
            }
            __syncthreads();
        }
        // normalize + write
        float inv[4];
        for (int r = 0; r < 4; r++) inv[r] = 1.0f / lrow[r];
        for (int j = 0; j < 4; j++)
            for (int r = 0; r < 4; r++)
                Obh[(size_t)(qrow0 + w * 16 + q * 4 + r) * 1024 + j * 16 + lane15] =
                    f2b(o[j][r] * inv[r]);
    }
}

// ---------------------------------------------------------------------------
// y = LN(X)*g + b + res; all fp32 in; writes bf16 (outB) and/or fp32 (outF)
// ---------------------------------------------------------------------------
__global__ __launch_bounds__(256) void ln_res(
    const float* __restrict__ X, const float* __restrict__ res,
    const float* __restrict__ g, const float* __restrict__ bb,
    u16* __restrict__ outB, float* __restrict__ outF)
{
    const int w = threadIdx.x >> 6, lane = threadIdx.x & 63;
    const int row = blockIdx.x * 4 + w;
    const float* xr = X + (size_t)row * 1024;
    f32x4 v[4];
    float s = 0.f, ss = 0.f;
    for (int i = 0; i < 4; i++) {
        v[i] = *(const f32x4*)&xr[(i * 64 + lane) * 4];
        for (int k = 0; k < 4; k++) { s += v[i][k]; ss += v[i][k] * v[i][k]; }
    }
    for (int d = 1; d < 64; d <<= 1) { s += __shfl_xor(s, d); ss += __shfl_xor(ss, d); }
    const float mu = s * (1.f / 1024.f);
    const float var = ss * (1.f / 1024.f) - mu * mu;
    const float rstd = rsqrtf(var + 1e-5f);
    for (int i = 0; i < 4; i++) {
        const int c0 = (i * 64 + lane) * 4;
        f32x4 rv = *(const f32x4*)&res[(size_t)row * 1024 + c0];
        f32x4 gv = *(const f32x4*)&g[c0];
        f32x4 bv = *(const f32x4*)&bb[c0];
        f32x4 ov;
        for (int k = 0; k < 4; k++)
            ov[k] = (v[i][k] - mu) * rstd * gv[k] + bv[k] + rv[k];
        if (outF) *(f32x4*)&outF[(size_t)row * 1024 + c0] = ov;
        if (outB) {
            u16x4 ob;
            for (int k = 0; k < 4; k++) ob[k] = f2b(ov[k]);
            *(u16x4*)&outB[(size_t)row * 1024 + c0] = ob;
        }
    }
}

// ---------------------------------------------------------------------------
extern "C" void kernel_launch(void* const* d_in, const int* in_sizes, int n_in,
                              void* d_out, int out_size, void* d_ws, size_t ws_size,
                              hipStream_t stream)
{
    const float* x   = (const float*)d_in[0];
    const float* Wq  = (const float*)d_in[1];  const float* bq  = (const float*)d_in[2];
    const float* Wk  = (const float*)d_in[3];  const float* bk  = (const float*)d_in[4];
    const float* Wv  = (const float*)d_in[5];  const float* bv  = (const float*)d_in[6];
    const float* Wo  = (const float*)d_in[7];  const float* bo  = (const float*)d_in[8];
    const float* g1  = (const float*)d_in[9];  const float* b1  = (const float*)d_in[10];
    const float* W1  = (const float*)d_in[11]; const float* bm1 = (const float*)d_in[12];
    const float* W2  = (const float*)d_in[13]; const float* bm2 = (const float*)d_in[14];
    const float* g2  = (const float*)d_in[15]; const float* b2  = (const float*)d_in[16];

    // workspace (84 MB, lifetime-aliased); MB = 1 MiB
    const size_t MB = (size_t)1 << 20;
    char* ws = (char*)d_ws;
    u16* xhi    = (u16*)(ws + 0 * MB);    // [split .. V-proj]
    u16* xlo    = (u16*)(ws + 8 * MB);    // [split .. QK gemm]
    u16* WqkThi = (u16*)(ws + 16 * MB);   // [.. QK gemm]
    u16* WqkTlo = (u16*)(ws + 20 * MB);   // [.. QK gemm]
    u16* WvT    = (u16*)(ws + 24 * MB);   // [.. V-proj]
    u16* Qhi    = (u16*)(ws + 26 * MB);   // [QK gemm .. attn]
    u16* Qlo    = (u16*)(ws + 34 * MB);
    u16* Khi    = (u16*)(ws + 42 * MB);
    u16* Klo    = (u16*)(ws + 50 * MB);
    u16* Vtb    = (u16*)(ws + 58 * MB);   // [V-proj .. attn]
    u16* WoT    = (u16*)(ws + 66 * MB);   // [.. o-proj]
    u16* W1T    = (u16*)(ws + 68 * MB);   // [.. FFN1]
    u16* W2T    = (u16*)(ws + 76 * MB);   // [.. FFN2]
    u16* aout   = (u16*)(ws + 16 * MB);   // [attn .. o-proj]  (over WqkT)
    float* Obuf = (float*)(ws + 26 * MB); // [o-proj .. ln1]   (over Qhi/Qlo)
    u16* x1b    = (u16*)(ws + 42 * MB);   // [ln1 .. FFN1]     (over Khi)
    float* x1f  = (float*)(ws + 50 * MB); // [ln1 .. ln2]      (over Klo/Vtb)
    u16* Hbh    = (u16*)(ws + 0 * MB);    // [FFN1 .. FFN2]    (over xhi/xlo)
    float* H2   = (float*)(ws + 26 * MB); // [FFN2 .. ln2]     (over Obuf)

    // splits / casts / transposes
    split_f32<<<4096, 256, 0, stream>>>(x, xhi, xlo);
    transpose_split_f32<<<dim3(32, 32), 256, 0, stream>>>(Wq, WqkThi, WqkTlo, 1024, 1024);
    transpose_split_f32<<<dim3(32, 32), 256, 0, stream>>>(Wk, WqkThi + 1024 * 1024,
                                                          WqkTlo + 1024 * 1024, 1024, 1024);
    transpose_f32_bf16<<<dim3(32, 32), 256, 0, stream>>>(Wv, WvT, 1024, 1024);
    transpose_f32_bf16<<<dim3(32, 32), 256, 0, stream>>>(Wo, WoT, 1024, 1024);
    transpose_f32_bf16<<<dim3(128, 32), 256, 0, stream>>>(W1, W1T, 1024, 4096);
    transpose_f32_bf16<<<dim3(32, 128), 256, 0, stream>>>(W2, W2T, 4096, 1024);

    // Q,K projection in bf16x3 (precision-critical: *8 logit amplification)
    gemm_qk_x3<<<dim3(16, 32), 256, 0, stream>>>(xhi, xlo, WqkThi, WqkTlo, bq, bk,
                                                 Qhi, Qlo, Khi, Klo);
    // V projection (plain bf16, V^T layout)
    gemm_bt<<<dim3(8, 32), 256, 0, stream>>>(xhi, WvT, bv, 4096, 1024, 1024,
                                             MODE_VT, nullptr, Vtb);

    attn_fwd<<<dim3(512), 256, 0, stream>>>(Qhi, Qlo, Khi, Klo, Vtb, aout);

    // out projection -> fp32
    gemm_bt<<<dim3(8, 32), 256, 0, stream>>>(aout, WoT, bo, 4096, 1024, 1024,
                                             MODE_F32, Obuf, nullptr);
    ln_res<<<1024, 256, 0, stream>>>(Obuf, x, g1, b1, x1b, x1f);

    // FFN in two M-halves (16 MB hidden buffer)
    for (int half = 0; half < 2; half++) {
        const size_t ro = (size_t)half * 2048;
        gemm_bt<<<dim3(32, 16), 256, 0, stream>>>(x1b + ro * 1024, W1T, bm1, 2048, 4096, 1024,
                                                  MODE_GELU, nullptr, Hbh);
        gemm_bt<<<dim3(8, 16), 256, 0, stream>>>(Hbh, W2T, bm2, 2048, 1024, 4096,
                                                 MODE_F32, H2 + ro * 1024, nullptr);
    }
    ln_res<<<1024, 256, 0, stream>>>(H2, x1f, g2, b2, nullptr, (float*)d_out);
}

// Round 5
// 1199.950 us; speedup vs baseline: 1.2674x; 1.2674x over previous
//
#include <hip/hip_runtime.h>
#include <stdint.h>

typedef unsigned short u16;
typedef short short8 __attribute__((ext_vector_type(8)));
typedef float f32x4 __attribute__((ext_vector_type(4)));
typedef u16 u16x4 __attribute__((ext_vector_type(4)));

#define MODE_F32  0
#define MODE_GELU 2
#define MODE_VT   4

__device__ __forceinline__ float b2f(u16 v) {
    union { uint32_t u; float f; } x; x.u = ((uint32_t)v) << 16; return x.f;
}
__device__ __forceinline__ u16 f2b(float f) {
    union { float f; uint32_t u; } x; x.f = f;
    uint32_t u = x.u;
    return (u16)((u + 0x7FFFu + ((u >> 16) & 1u)) >> 16);   // RNE
}

// async global->LDS, 16B per lane; LDS dest is wave-uniform base + lane*16
#define ASYNC16(gp, lp)                                                        \
    __builtin_amdgcn_global_load_lds(                                          \
        (const __attribute__((address_space(1))) uint32_t*)(const void*)(gp),  \
        (__attribute__((address_space(3))) uint32_t*)(void*)(lp), 16, 0, 0)

#define MFMA16(a, b, c) __builtin_amdgcn_mfma_f32_16x16x32_bf16((a), (b), (c), 0, 0, 0)

// ---------------------------------------------------------------------------
// fp32 -> (hi, lo) bf16 split:  x ~= b2f(hi) + b2f(lo)
// ---------------------------------------------------------------------------
__global__ __launch_bounds__(256) void split_f32(
    const float* __restrict__ in, u16* __restrict__ hi, u16* __restrict__ lo)
{
    const int i = (blockIdx.x * 256 + threadIdx.x) * 4;
    f32x4 v = *(const f32x4*)&in[i];
    u16x4 h, l;
    for (int k = 0; k < 4; k++) {
        h[k] = f2b(v[k]);
        l[k] = f2b(v[k] - b2f(h[k]));
    }
    *(u16x4*)&hi[i] = h;
    *(u16x4*)&lo[i] = l;
}

// fp32 [rows,cols] -> bf16 [cols,rows] transpose+cast
__global__ __launch_bounds__(256) void transpose_f32_bf16(
    const float* __restrict__ in, u16* __restrict__ out, int rows, int cols)
{
    __shared__ float t[32][33];
    const int r0 = blockIdx.y * 32, c0 = blockIdx.x * 32;
    const int tr = threadIdx.x >> 3, tc = (threadIdx.x & 7) * 4;
    f32x4 v = *(const f32x4*)&in[(size_t)(r0 + tr) * cols + c0 + tc];
    for (int i = 0; i < 4; i++) t[tr][tc + i] = v[i];
    __syncthreads();
    u16x4 ov;
    for (int i = 0; i < 4; i++) ov[i] = f2b(t[tc + i][tr]);
    *(u16x4*)&out[(size_t)(c0 + tr) * rows + r0 + tc] = ov;
}

// fp32 [rows,cols] -> bf16 hi/lo [cols,rows] transpose+split
__global__ __launch_bounds__(256) void transpose_split_f32(
    const float* __restrict__ in, u16* __restrict__ hi, u16* __restrict__ lo,
    int rows, int cols)
{
    __shared__ float t[32][33];
    const int r0 = blockIdx.y * 32, c0 = blockIdx.x * 32;
    const int tr = threadIdx.x >> 3, tc = (threadIdx.x & 7) * 4;
    f32x4 v = *(const f32x4*)&in[(size_t)(r0 + tr) * cols + c0 + tc];
    for (int i = 0; i < 4; i++) t[tr][tc + i] = v[i];
    __syncthreads();
    u16x4 hv, lv;
    for (int i = 0; i < 4; i++) {
        const float f = t[tc + i][tr];
        hv[i] = f2b(f);
        lv[i] = f2b(f - b2f(hv[i]));
    }
    const size_t o = (size_t)(c0 + tr) * rows + r0 + tc;
    *(u16x4*)&hi[o] = hv;
    *(u16x4*)&lo[o] = lv;
}

// ---------------------------------------------------------------------------
// QK projection, bf16x3, double-buffered K-loop (1 barrier/iter)
// ---------------------------------------------------------------------------
__global__ __launch_bounds__(256) void gemm_qk_x3(
    const u16* __restrict__ Ahi, const u16* __restrict__ Alo,
    const u16* __restrict__ Bhi, const u16* __restrict__ Blo,
    const float* __restrict__ bq, const float* __restrict__ bk,
    u16* __restrict__ Qhi, u16* __restrict__ Qlo,
    u16* __restrict__ Khi, u16* __restrict__ Klo)
{
    const int K = 1024;
    __shared__ u16 lAh[2][4096], lAl[2][4096];
    __shared__ u16 lBh[2][4096], lBl[2][4096];

    const int tid = threadIdx.x;
    const int w = tid >> 6, lane = tid & 63;
    const int lane15 = lane & 15, q = lane >> 4;
    const int tM = blockIdx.y * 128, tN = blockIdx.x * 128;
    const int m0 = (w >> 1) * 64, n0 = (w & 1) * 64;

    f32x4 acc[4][4];
    for (int i = 0; i < 4; i++)
        for (int j = 0; j < 4; j++)
            acc[i][j] = (f32x4){0.f, 0.f, 0.f, 0.f};

    const int pa0 = 2 * w, pa1 = 2 * w + 1;
    const int srow = lane >> 2, sch = lane & 3;
    const u16* Ah = Ahi + (size_t)tM * K;
    const u16* Al = Alo + (size_t)tM * K;
    const u16* Bh = Bhi + (size_t)tN * K;
    const u16* Bl = Blo + (size_t)tN * K;
    const size_t r0 = (size_t)(pa0 * 16 + srow) * K + sch * 8;
    const size_t r1 = (size_t)(pa1 * 16 + srow) * K + sch * 8;

    // prologue: stage tile 0 into buf 0
    ASYNC16(Ah + r0, &lAh[0][pa0 * 512]);  ASYNC16(Ah + r1, &lAh[0][pa1 * 512]);
    ASYNC16(Al + r0, &lAl[0][pa0 * 512]);  ASYNC16(Al + r1, &lAl[0][pa1 * 512]);
    ASYNC16(Bh + r0, &lBh[0][pa0 * 512]);  ASYNC16(Bh + r1, &lBh[0][pa1 * 512]);
    ASYNC16(Bl + r0, &lBl[0][pa0 * 512]);  ASYNC16(Bl + r1, &lBl[0][pa1 * 512]);

    const int NT = K / 32;
    for (int kt = 0; kt < NT; kt++) {
        __syncthreads();   // tile kt resident; prior buf free for prefetch
        const int cur = kt & 1, nxt = cur ^ 1;
        if (kt + 1 < NT) {
            const int k0 = (kt + 1) * 32;
            ASYNC16(Ah + r0 + k0, &lAh[nxt][pa0 * 512]);  ASYNC16(Ah + r1 + k0, &lAh[nxt][pa1 * 512]);
            ASYNC16(Al + r0 + k0, &lAl[nxt][pa0 * 512]);  ASYNC16(Al + r1 + k0, &lAl[nxt][pa1 * 512]);
            ASYNC16(Bh + r0 + k0, &lBh[nxt][pa0 * 512]);  ASYNC16(Bh + r1 + k0, &lBh[nxt][pa1 * 512]);
            ASYNC16(Bl + r0 + k0, &lBl[nxt][pa0 * 512]);  ASYNC16(Bl + r1 + k0, &lBl[nxt][pa1 * 512]);
        }
        short8 afh[4], afl[4], bfh[4], bfl[4];
        for (int i = 0; i < 4; i++) {
            const int o = (m0 + i * 16 + lane15) * 32 + q * 8;
            afh[i] = *(const short8*)&lAh[cur][o];
            afl[i] = *(const short8*)&lAl[cur][o];
        }
        for (int j = 0; j < 4; j++) {
            const int o = (n0 + j * 16 + lane15) * 32 + q * 8;
            bfh[j] = *(const short8*)&lBh[cur][o];
            bfl[j] = *(const short8*)&lBl[cur][o];
        }
        for (int i = 0; i < 4; i++)
            for (int j = 0; j < 4; j++) {
                acc[i][j] = MFMA16(afh[i], bfh[j], acc[i][j]);
                acc[i][j] = MFMA16(afh[i], bfl[j], acc[i][j]);
                acc[i][j] = MFMA16(afl[i], bfh[j], acc[i][j]);
            }
    }

    for (int i = 0; i < 4; i++) {
        const int rb = tM + m0 + i * 16 + q * 4;
        for (int j = 0; j < 4; j++) {
            const int col = tN + n0 + j * 16 + lane15;
            const float bv = (col < 1024) ? bq[col] : bk[col - 1024];
            for (int r = 0; r < 4; r++) {
                const int row = rb + r;
                const float v = acc[i][j][r] + bv;
                const u16 hv = f2b(v);
                const u16 lv = f2b(v - b2f(hv));
                if (col < 1024) {
                    Qhi[(size_t)row * 1024 + col] = hv;
                    Qlo[(size_t)row * 1024 + col] = lv;
                } else {
                    Khi[(size_t)row * 1024 + col - 1024] = hv;
                    Klo[(size_t)row * 1024 + col - 1024] = lv;
                }
            }
        }
    }
}

// ---------------------------------------------------------------------------
// C = A[M,K] * Bt[N,K]^T + bias; double-buffered K-loop (1 barrier/iter)
// ---------------------------------------------------------------------------
__global__ __launch_bounds__(256) void gemm_bt(
    const u16* __restrict__ A, const u16* __restrict__ Bt, const float* __restrict__ bias,
    int M, int N, int K, int mode,
    float* __restrict__ outF, u16* __restrict__ outB)
{
    __shared__ u16 lA[2][4096];
    __shared__ u16 lB[2][4096];

    const int tid = threadIdx.x;
    const int w = tid >> 6, lane = tid & 63;
    const int lane15 = lane & 15, q = lane >> 4;
    const int tM = blockIdx.y * 128, tN = blockIdx.x * 128;
    const int m0 = (w >> 1) * 64, n0 = (w & 1) * 64;

    f32x4 acc[4][4];
    for (int i = 0; i < 4; i++)
        for (int j = 0; j < 4; j++)
            acc[i][j] = (f32x4){0.f, 0.f, 0.f, 0.f};

    const int pa0 = 2 * w, pa1 = 2 * w + 1;
    const int srow = lane >> 2, sch = lane & 3;
    const u16* Abase = A + (size_t)tM * K;
    const u16* Bbase = Bt + (size_t)tN * K;
    const size_t r0 = (size_t)(pa0 * 16 + srow) * K + sch * 8;
    const size_t r1 = (size_t)(pa1 * 16 + srow) * K + sch * 8;

    ASYNC16(Abase + r0, &lA[0][pa0 * 512]);
    ASYNC16(Abase + r1, &lA[0][pa1 * 512]);
    ASYNC16(Bbase + r0, &lB[0][pa0 * 512]);
    ASYNC16(Bbase + r1, &lB[0][pa1 * 512]);

    const int NT = K / 32;
    for (int kt = 0; kt < NT; kt++) {
        __syncthreads();
        const int cur = kt & 1, nxt = cur ^ 1;
        if (kt + 1 < NT) {
            const int k0 = (kt + 1) * 32;
            ASYNC16(Abase + r0 + k0, &lA[nxt][pa0 * 512]);
            ASYNC16(Abase + r1 + k0, &lA[nxt][pa1 * 512]);
            ASYNC16(Bbase + r0 + k0, &lB[nxt][pa0 * 512]);
            ASYNC16(Bbase + r1 + k0, &lB[nxt][pa1 * 512]);
        }
        short8 af[4], bf[4];
        for (int i = 0; i < 4; i++) af[i] = *(const short8*)&lA[cur][(m0 + i * 16 + lane15) * 32 + q * 8];
        for (int j = 0; j < 4; j++) bf[j] = *(const short8*)&lB[cur][(n0 + j * 16 + lane15) * 32 + q * 8];
        for (int i = 0; i < 4; i++)
            for (int j = 0; j < 4; j++)
                acc[i][j] = MFMA16(af[i], bf[j], acc[i][j]);
    }

    for (int i = 0; i < 4; i++) {
        const int rb = tM + m0 + i * 16 + q * 4;
        for (int j = 0; j < 4; j++) {
            const int col = tN + n0 + j * 16 + lane15;
            const float bv = bias ? bias[col] : 0.f;
            for (int r = 0; r < 4; r++) {
                const int row = rb + r;
                float v = acc[i][j][r] + bv;
                if (mode == MODE_F32) {
                    outF[(size_t)row * N + col] = v;
                } else if (mode == MODE_GELU) {
                    v = 0.5f * v * (1.f + erff(v * 0.70710678118f));
                    outB[(size_t)row * N + col] = f2b(v);
                } else {  // MODE_VT: V^T per (b,h): out[((b*16+h)*64+d)*2048 + n]
                    const int bb = row >> 11, n = row & 2047;
                    outB[((size_t)(bb * 16 + (col >> 6)) * 64 + (col & 63)) * 2048 + n] = f2b(v);
                }
            }
        }
    }
}

// ---------------------------------------------------------------------------
// Flash attention with bf16x3 QK^T (unchanged from passing round 4)
// ---------------------------------------------------------------------------
__global__ __launch_bounds__(256) void attn_fwd(
    const u16* __restrict__ Qhig, const u16* __restrict__ Qlog,
    const u16* __restrict__ Khig, const u16* __restrict__ Klog,
    const u16* __restrict__ Vtg, u16* __restrict__ Og)
{
    __shared__ u16 lQh[2][2048], lQl[2][2048];
    __shared__ u16 lKh[2][1024], lKl[2][1024];
    __shared__ u16 lV[2048];
    __shared__ u16 lP[4][640];

    const int tid = threadIdx.x, w = tid >> 6, lane = tid & 63;
    const int lane15 = lane & 15, q = lane >> 4;
    const int bh = blockIdx.x >> 4, pair = blockIdx.x & 15;
    const int b = bh >> 4, h = bh & 15;

    const size_t xoff = (size_t)b * 2048 * 1024 + h * 64;
    const u16* Qh_ = Qhig + xoff;
    const u16* Ql_ = Qlog + xoff;
    const u16* Kh_ = Khig + xoff;
    const u16* Kl_ = Klog + xoff;
    const u16* Vbh = Vtg + (size_t)bh * 64 * 2048;
    u16* Obh = Og + xoff;

    const int srow = lane >> 2, sch = lane & 3;
    const float NEG = -3.0e38f;

    for (int half = 0; half < 2; half++) {
        const int qb = half ? (31 - pair) : pair;
        const int qrow0 = qb * 64;
        const int ntiles = 2 * qb + 2;

        for (int ii = 0; ii < 4; ii++) {
            const int id = w * 4 + ii;
            const int idq = id & 7, ks = idq >> 2, p = idq & 3;
            const size_t so = (size_t)(qrow0 + p * 16 + srow) * 1024 + ks * 32 + sch * 8;
            if (id < 8) ASYNC16(Qh_ + so, &lQh[ks][p * 512]);
            else        ASYNC16(Ql_ + so, &lQl[ks][p * 512]);
        }

        f32x4 o[4];
        for (int j = 0; j < 4; j++) o[j] = (f32x4){0.f, 0.f, 0.f, 0.f};
        float mrow[4], lrow[4];
        for (int r = 0; r < 4; r++) { mrow[r] = NEG; lrow[r] = 0.f; }
        short8 aqh0 = {}, aqh1 = {}, aql0 = {}, aql1 = {};
        bool first = true;

        for (int t = 0; t < ntiles; t++) {
            const int kk0 = t * 32;
            for (int ii = 0; ii < 3; ii++) {
                const int id = w * 3 + ii;
                if (id < 8) {
                    const int sel = id >> 2, idk = id & 3, ks = idk >> 1, hh = idk & 1;
                    const size_t so = (size_t)(kk0 + hh * 16 + srow) * 1024 + ks * 32 + sch * 8;
                    if (sel == 0) ASYNC16(Kh_ + so, &lKh[ks][hh * 512]);
                    else          ASYNC16(Kl_ + so, &lKl[ks][hh * 512]);
                } else {
                    const int p = id - 8;
                    ASYNC16(Vbh + (size_t)(p * 16 + srow) * 2048 + kk0 + sch * 8, &lV[p * 512]);
                }
            }
            __syncthreads();
            if (first) {
                const int o0 = (w * 16 + lane15) * 32 + q * 8;
                aqh0 = *(const short8*)&lQh[0][o0];
                aqh1 = *(const short8*)&lQh[1][o0];
                aql0 = *(const short8*)&lQl[0][o0];
                aql1 = *(const short8*)&lQl[1][o0];
                first = false;
            }
            f32x4 s[2];
            for (int sub = 0; sub < 2; sub++) {
                const int ko = (sub * 16 + lane15) * 32 + q * 8;
                short8 bkh0 = *(const short8*)&lKh[0][ko];
                short8 bkh1 = *(const short8*)&lKh[1][ko];
                short8 bkl0 = *(const short8*)&lKl[0][ko];
                short8 bkl1 = *(const short8*)&lKl[1][ko];
                f32x4 z = (f32x4){0.f, 0.f, 0.f, 0.f};
                z = MFMA16(aqh0, bkh0, z);
                z = MFMA16(aqh1, bkh1, z);
                z = MFMA16(aqh0, bkl0, z);
                z = MFMA16(aqh1, bkl1, z);
                z = MFMA16(aql0, bkh0, z);
                z = MFMA16(aql1, bkh1, z);
                s[sub] = z;
            }
            const int rbase = qrow0 + w * 16 + q * 4;
            for (int sub = 0; sub < 2; sub++)
                for (int r = 0; r < 4; r++) {
                    const int key = kk0 + sub * 16 + lane15;
                    float sv = s[sub][r] * 8.0f;
                    if (key > rbase + r) sv = NEG;
                    s[sub][r] = sv;
                }
            float mx[4];
            for (int r = 0; r < 4; r++) mx[r] = fmaxf(s[0][r], s[1][r]);
            for (int d = 1; d < 16; d <<= 1)
                for (int r = 0; r < 4; r++) mx[r] = fmaxf(mx[r], __shfl_xor(mx[r], d));
            float alpha[4];
            for (int r = 0; r < 4; r++) {
                const float mnew = fmaxf(mrow[r], mx[r]);
                alpha[r] = __expf(mrow[r] - mnew);
                mrow[r] = mnew;
            }
            float rsum[4] = {0.f, 0.f, 0.f, 0.f};
            for (int sub = 0; sub < 2; sub++)
                for (int r = 0; r < 4; r++) {
                    const float p = __expf(s[sub][r] - mrow[r]);
                    rsum[r] += p;
                    lP[w][(q * 4 + r) * 40 + sub * 16 + lane15] = f2b(p);
                }
            for (int d = 1; d < 16; d <<= 1)
                for (int r = 0; r < 4; r++) rsum[r] += __shfl_xor(rsum[r], d);
            for (int r = 0; r < 4; r++) lrow[r] = lrow[r] * alpha[r] + rsum[r];
            for (int j = 0; j < 4; j++)
                for (int r = 0; r < 4; r++) o[j][r] *= alpha[r];
            short8 ap = *(const short8*)&lP[w][lane15 * 40 + q * 8];
            for (int j = 0; j < 4; j++) {
                short8 bv = *(const short8*)&lV[(j * 16 + lane15) * 32 + q * 8];
                o[j] = MFMA16(ap, bv, o[j]);
            }
            __syncthreads();
        }
        float inv[4];
        for (int r = 0; r < 4; r++) inv[r] = 1.0f / lrow[r];
        for (int j = 0; j < 4; j++)
            for (int r = 0; r < 4; r++)
                Obh[(size_t)(qrow0 + w * 16 + q * 4 + r) * 1024 + j * 16 + lane15] =
                    f2b(o[j][r] * inv[r]);
    }
}

// ---------------------------------------------------------------------------
// y = LN(X)*g + b + res; all fp32; writes bf16 (outB) and/or fp32 (outF)
// ---------------------------------------------------------------------------
__global__ __launch_bounds__(256) void ln_res(
    const float* __restrict__ X, const float* __restrict__ res,
    const float* __restrict__ g, const float* __restrict__ bb,
    u16* __restrict__ outB, float* __restrict__ outF)
{
    const int w = threadIdx.x >> 6, lane = threadIdx.x & 63;
    const int row = blockIdx.x * 4 + w;
    const float* xr = X + (size_t)row * 1024;
    f32x4 v[4];
    float s = 0.f, ss = 0.f;
    for (int i = 0; i < 4; i++) {
        v[i] = *(const f32x4*)&xr[(i * 64 + lane) * 4];
        for (int k = 0; k < 4; k++) { s += v[i][k]; ss += v[i][k] * v[i][k]; }
    }
    for (int d = 1; d < 64; d <<= 1) { s += __shfl_xor(s, d); ss += __shfl_xor(ss, d); }
    const float mu = s * (1.f / 1024.f);
    const float var = ss * (1.f / 1024.f) - mu * mu;
    const float rstd = rsqrtf(var + 1e-5f);
    for (int i = 0; i < 4; i++) {
        const int c0 = (i * 64 + lane) * 4;
        f32x4 rv = *(const f32x4*)&res[(size_t)row * 1024 + c0];
        f32x4 gv = *(const f32x4*)&g[c0];
        f32x4 bv = *(const f32x4*)&bb[c0];
        f32x4 ov;
        for (int k = 0; k < 4; k++)
            ov[k] = (v[i][k] - mu) * rstd * gv[k] + bv[k] + rv[k];
        if (outF) *(f32x4*)&outF[(size_t)row * 1024 + c0] = ov;
        if (outB) {
            u16x4 ob;
            for (int k = 0; k < 4; k++) ob[k] = f2b(ov[k]);
            *(u16x4*)&outB[(size_t)row * 1024 + c0] = ob;
        }
    }
}

// ---------------------------------------------------------------------------
extern "C" void kernel_launch(void* const* d_in, const int* in_sizes, int n_in,
                              void* d_out, int out_size, void* d_ws, size_t ws_size,
                              hipStream_t stream)
{
    const float* x   = (const float*)d_in[0];
    const float* Wq  = (const float*)d_in[1];  const float* bq  = (const float*)d_in[2];
    const float* Wk  = (const float*)d_in[3];  const float* bk  = (const float*)d_in[4];
    const float* Wv  = (const float*)d_in[5];  const float* bv  = (const float*)d_in[6];
    const float* Wo  = (const float*)d_in[7];  const float* bo  = (const float*)d_in[8];
    const float* g1  = (const float*)d_in[9];  const float* b1  = (const float*)d_in[10];
    const float* W1  = (const float*)d_in[11]; const float* bm1 = (const float*)d_in[12];
    const float* W2  = (const float*)d_in[13]; const float* bm2 = (const float*)d_in[14];
    const float* g2  = (const float*)d_in[15]; const float* b2  = (const float*)d_in[16];

    // workspace (88 MB peak, lifetime-aliased); MB = 1 MiB
    const size_t MB = (size_t)1 << 20;
    char* ws = (char*)d_ws;
    u16* xhi    = (u16*)(ws + 0 * MB);    // [split .. V-proj]
    u16* xlo    = (u16*)(ws + 8 * MB);    // [split .. QK gemm]
    u16* WqkThi = (u16*)(ws + 16 * MB);   // [.. QK gemm]
    u16* WqkTlo = (u16*)(ws + 20 * MB);   // [.. QK gemm]
    u16* WvT    = (u16*)(ws + 24 * MB);   // [.. V-proj]
    u16* WoT    = (u16*)(ws + 26 * MB);   // [.. o-proj]
    u16* W1T    = (u16*)(ws + 32 * MB);   // [.. FFN1]
    u16* W2T    = (u16*)(ws + 40 * MB);   // [.. FFN2]
    u16* Qhi    = (u16*)(ws + 48 * MB);   // [QK gemm .. attn]
    u16* Qlo    = (u16*)(ws + 56 * MB);
    u16* Khi    = (u16*)(ws + 64 * MB);
    u16* Klo    = (u16*)(ws + 72 * MB);
    u16* Vtb    = (u16*)(ws + 80 * MB);   // [V-proj .. attn]
    u16* aout   = (u16*)(ws + 16 * MB);   // [attn .. o-proj]  (over WqkT)
    float* Obuf = (float*)(ws + 48 * MB); // [o-proj .. ln1]   (over Qhi/Qlo)
    u16* x1b    = (u16*)(ws + 64 * MB);   // [ln1 .. FFN1]     (over Khi)
    float* x1f  = (float*)(ws + 72 * MB); // [ln1 .. ln2]      (over Klo/Vtb)
    u16* Hb     = (u16*)(ws + 0 * MB);    // [FFN1 .. FFN2]    (0..32, over xhi/xlo/aout/WvT/WoT)
    float* H2   = (float*)(ws + 48 * MB); // [FFN2 .. ln2]     (over Obuf)

    // splits / casts / transposes
    split_f32<<<4096, 256, 0, stream>>>(x, xhi, xlo);
    transpose_split_f32<<<dim3(32, 32), 256, 0, stream>>>(Wq, WqkThi, WqkTlo, 1024, 1024);
    transpose_split_f32<<<dim3(32, 32), 256, 0, stream>>>(Wk, WqkThi + 1024 * 1024,
                                                          WqkTlo + 1024 * 1024, 1024, 1024);
    transpose_f32_bf16<<<dim3(32, 32), 256, 0, stream>>>(Wv, WvT, 1024, 1024);
    transpose_f32_bf16<<<dim3(32, 32), 256, 0, stream>>>(Wo, WoT, 1024, 1024);
    transpose_f32_bf16<<<dim3(128, 32), 256, 0, stream>>>(W1, W1T, 1024, 4096);
    transpose_f32_bf16<<<dim3(32, 128), 256, 0, stream>>>(W2, W2T, 4096, 1024);

    // Q,K projection in bf16x3 (precision-critical: *8 logit amplification)
    gemm_qk_x3<<<dim3(16, 32), 256, 0, stream>>>(xhi, xlo, WqkThi, WqkTlo, bq, bk,
                                                 Qhi, Qlo, Khi, Klo);
    // V projection (plain bf16, V^T layout)
    gemm_bt<<<dim3(8, 32), 256, 0, stream>>>(xhi, WvT, bv, 4096, 1024, 1024,
                                             MODE_VT, nullptr, Vtb);

    attn_fwd<<<dim3(512), 256, 0, stream>>>(Qhi, Qlo, Khi, Klo, Vtb, aout);

    // out projection -> fp32
    gemm_bt<<<dim3(8, 32), 256, 0, stream>>>(aout, WoT, bo, 4096, 1024, 1024,
                                             MODE_F32, Obuf, nullptr);
    ln_res<<<1024, 256, 0, stream>>>(Obuf, x, g1, b1, x1b, x1f);

    // FFN, full M (1024-block FFN1)
    gemm_bt<<<dim3(32, 32), 256, 0, stream>>>(x1b, W1T, bm1, 4096, 4096, 1024,
                                              MODE_GELU, nullptr, Hb);
    gemm_bt<<<dim3(8, 32), 256, 0, stream>>>(Hb, W2T, bm2, 4096, 1024, 4096,
                                             MODE_F32, H2, nullptr);
    ln_res<<<1024, 256, 0, stream>>>(H2, x1f, g2, b2, nullptr, (float*)d_out);
}

// Round 6
// 510.399 us; speedup vs baseline: 2.9796x; 2.3510x over previous
//
#include <hip/hip_runtime.h>
#include <stdint.h>

typedef unsigned short u16;
typedef short short8 __attribute__((ext_vector_type(8)));
typedef float f32x4 __attribute__((ext_vector_type(4)));
typedef u16 u16x4 __attribute__((ext_vector_type(4)));
typedef u16 u16x8 __attribute__((ext_vector_type(8)));

#define MODE_F32  0
#define MODE_GELU 2
#define MODE_VT   4

__device__ __forceinline__ float b2f(u16 v) {
    union { uint32_t u; float f; } x; x.u = ((uint32_t)v) << 16; return x.f;
}
__device__ __forceinline__ u16 f2b(float f) {
    union { float f; uint32_t u; } x; x.f = f;
    uint32_t u = x.u;
    return (u16)((u + 0x7FFFu + ((u >> 16) & 1u)) >> 16);   // RNE
}

// async global->LDS, 16B per lane; LDS dest is wave-uniform base + lane*16
#define ASYNC16(gp, lp)                                                        \
    __builtin_amdgcn_global_load_lds(                                          \
        (const __attribute__((address_space(1))) uint32_t*)(const void*)(gp),  \
        (__attribute__((address_space(3))) uint32_t*)(void*)(lp), 16, 0, 0)

#define MFMA16(a, b, c) __builtin_amdgcn_mfma_f32_16x16x32_bf16((a), (b), (c), 0, 0, 0)

// ---------------------------------------------------------------------------
// fp32 -> (hi, lo) bf16 split
// ---------------------------------------------------------------------------
__global__ __launch_bounds__(256) void split_f32(
    const float* __restrict__ in, u16* __restrict__ hi, u16* __restrict__ lo)
{
    const int i = (blockIdx.x * 256 + threadIdx.x) * 4;
    f32x4 v = *(const f32x4*)&in[i];
    u16x4 h, l;
    for (int k = 0; k < 4; k++) {
        h[k] = f2b(v[k]);
        l[k] = f2b(v[k] - b2f(h[k]));
    }
    *(u16x4*)&hi[i] = h;
    *(u16x4*)&lo[i] = l;
}

// fp32 [rows,cols] -> bf16 [cols,rows] transpose+cast
__global__ __launch_bounds__(256) void transpose_f32_bf16(
    const float* __restrict__ in, u16* __restrict__ out, int rows, int cols)
{
    __shared__ float t[32][33];
    const int r0 = blockIdx.y * 32, c0 = blockIdx.x * 32;
    const int tr = threadIdx.x >> 3, tc = (threadIdx.x & 7) * 4;
    f32x4 v = *(const f32x4*)&in[(size_t)(r0 + tr) * cols + c0 + tc];
    for (int i = 0; i < 4; i++) t[tr][tc + i] = v[i];
    __syncthreads();
    u16x4 ov;
    for (int i = 0; i < 4; i++) ov[i] = f2b(t[tc + i][tr]);
    *(u16x4*)&out[(size_t)(c0 + tr) * rows + r0 + tc] = ov;
}

// fp32 [rows,cols] -> bf16 hi/lo [cols,rows] transpose+split
__global__ __launch_bounds__(256) void transpose_split_f32(
    const float* __restrict__ in, u16* __restrict__ hi, u16* __restrict__ lo,
    int rows, int cols)
{
    __shared__ float t[32][33];
    const int r0 = blockIdx.y * 32, c0 = blockIdx.x * 32;
    const int tr = threadIdx.x >> 3, tc = (threadIdx.x & 7) * 4;
    f32x4 v = *(const f32x4*)&in[(size_t)(r0 + tr) * cols + c0 + tc];
    for (int i = 0; i < 4; i++) t[tr][tc + i] = v[i];
    __syncthreads();
    u16x4 hv, lv;
    for (int i = 0; i < 4; i++) {
        const float f = t[tc + i][tr];
        hv[i] = f2b(f);
        lv[i] = f2b(f - b2f(hv[i]));
    }
    const size_t o = (size_t)(c0 + tr) * rows + r0 + tc;
    *(u16x4*)&hi[o] = hv;
    *(u16x4*)&lo[o] = lv;
}

// ---------------------------------------------------------------------------
// QK projection, bf16x3, double-buffered; coalesced hi/lo epilogue via LDS
// ---------------------------------------------------------------------------
__global__ __launch_bounds__(256) void gemm_qk_x3(
    const u16* __restrict__ Ahi, const u16* __restrict__ Alo,
    const u16* __restrict__ Bhi, const u16* __restrict__ Blo,
    const float* __restrict__ bq, const float* __restrict__ bk,
    u16* __restrict__ Qhi, u16* __restrict__ Qlo,
    u16* __restrict__ Khi, u16* __restrict__ Klo)
{
    const int K = 1024;
    __shared__ __align__(16) u16 SM[32768];   // 64 KB: 4 staged operands x dbuf
    u16* lAh = SM;          u16* lAl = SM + 8192;
    u16* lBh = SM + 16384;  u16* lBl = SM + 24576;

    const int tid = threadIdx.x;
    const int w = tid >> 6, lane = tid & 63;
    const int lane15 = lane & 15, q = lane >> 4;
    const int tM = blockIdx.y * 128, tN = blockIdx.x * 128;
    const int m0 = (w >> 1) * 64, n0 = (w & 1) * 64;

    f32x4 acc[4][4];
    for (int i = 0; i < 4; i++)
        for (int j = 0; j < 4; j++)
            acc[i][j] = (f32x4){0.f, 0.f, 0.f, 0.f};

    const int pa0 = 2 * w, pa1 = 2 * w + 1;
    const int srow = lane >> 2, sch = lane & 3;
    const u16* Ah = Ahi + (size_t)tM * K;
    const u16* Al = Alo + (size_t)tM * K;
    const u16* Bh = Bhi + (size_t)tN * K;
    const u16* Bl = Blo + (size_t)tN * K;
    const size_t r0 = (size_t)(pa0 * 16 + srow) * K + sch * 8;
    const size_t r1 = (size_t)(pa1 * 16 + srow) * K + sch * 8;

    ASYNC16(Ah + r0, lAh + pa0 * 512);  ASYNC16(Ah + r1, lAh + pa1 * 512);
    ASYNC16(Al + r0, lAl + pa0 * 512);  ASYNC16(Al + r1, lAl + pa1 * 512);
    ASYNC16(Bh + r0, lBh + pa0 * 512);  ASYNC16(Bh + r1, lBh + pa1 * 512);
    ASYNC16(Bl + r0, lBl + pa0 * 512);  ASYNC16(Bl + r1, lBl + pa1 * 512);

    const int NT = K / 32;
    for (int kt = 0; kt < NT; kt++) {
        __syncthreads();
        const int cb = (kt & 1) * 4096, nb = 4096 - cb;
        if (kt + 1 < NT) {
            const int k0 = (kt + 1) * 32;
            ASYNC16(Ah + r0 + k0, lAh + nb + pa0 * 512);  ASYNC16(Ah + r1 + k0, lAh + nb + pa1 * 512);
            ASYNC16(Al + r0 + k0, lAl + nb + pa0 * 512);  ASYNC16(Al + r1 + k0, lAl + nb + pa1 * 512);
            ASYNC16(Bh + r0 + k0, lBh + nb + pa0 * 512);  ASYNC16(Bh + r1 + k0, lBh + nb + pa1 * 512);
            ASYNC16(Bl + r0 + k0, lBl + nb + pa0 * 512);  ASYNC16(Bl + r1 + k0, lBl + nb + pa1 * 512);
        }
        short8 afh[4], afl[4], bfh[4], bfl[4];
        for (int i = 0; i < 4; i++) {
            const int o = cb + (m0 + i * 16 + lane15) * 32 + q * 8;
            afh[i] = *(const short8*)&lAh[o];
            afl[i] = *(const short8*)&lAl[o];
        }
        for (int j = 0; j < 4; j++) {
            const int o = cb + (n0 + j * 16 + lane15) * 32 + q * 8;
            bfh[j] = *(const short8*)&lBh[o];
            bfl[j] = *(const short8*)&lBl[o];
        }
        for (int i = 0; i < 4; i++)
            for (int j = 0; j < 4; j++) {
                acc[i][j] = MFMA16(afh[i], bfh[j], acc[i][j]);
                acc[i][j] = MFMA16(afh[i], bfl[j], acc[i][j]);
                acc[i][j] = MFMA16(afl[i], bfh[j], acc[i][j]);
            }
    }

    // epilogue: block writes Q (tN<1024) or K; two passes (hi, lo) through LDS
    const bool isQ = (tN < 1024);
    u16* dhi = isQ ? Qhi : Khi;
    u16* dlo = isQ ? Qlo : Klo;
    const int cN = isQ ? tN : (tN - 1024);
    u16* sC = SM;   // 128 x 136 = 17408 u16, fits in staging LDS
    for (int pass = 0; pass < 2; pass++) {
        __syncthreads();
        for (int i = 0; i < 4; i++) {
            const int rl0 = m0 + i * 16 + q * 4;
            for (int j = 0; j < 4; j++) {
                const int cl = n0 + j * 16 + lane15;
                const float bv = isQ ? bq[cN + cl] : bk[cN + cl];
                for (int r = 0; r < 4; r++) {
                    const float v = acc[i][j][r] + bv;
                    const u16 hv = f2b(v);
                    sC[(rl0 + r) * 136 + cl] = pass == 0 ? hv : f2b(v - b2f(hv));
                }
            }
        }
        __syncthreads();
        u16* dst = pass == 0 ? dhi : dlo;
        for (int t8 = 0; t8 < 8; t8++) {
            const int rl = t8 * 16 + (tid >> 4), cl = (tid & 15) * 8;
            *(u16x8*)&dst[(size_t)(tM + rl) * 1024 + cN + cl] = *(const u16x8*)&sC[rl * 136 + cl];
        }
    }
}

// ---------------------------------------------------------------------------
// C = A[M,K] * Bt[N,K]^T + bias; dbuf K-loop; optional split-K via gridDim.z
// bf16 outputs staged through LDS for full-line coalesced writes
// ---------------------------------------------------------------------------
__global__ __launch_bounds__(256) void gemm_bt(
    const u16* __restrict__ A, const u16* __restrict__ Bt, const float* __restrict__ bias,
    int M, int N, int K, int mode,
    float* __restrict__ outF, u16* __restrict__ outB, size_t pstride)
{
    __shared__ __align__(16) u16 SM[17408];   // staging 16384 + epilogue needs 17408
    u16* lA = SM;
    u16* lB = SM + 8192;

    const int tid = threadIdx.x;
    const int w = tid >> 6, lane = tid & 63;
    const int lane15 = lane & 15, q = lane >> 4;
    const int tM = blockIdx.y * 128, tN = blockIdx.x * 128;
    const int m0 = (w >> 1) * 64, n0 = (w & 1) * 64;

    const int kchunk = K / gridDim.z;
    const int koff = blockIdx.z * kchunk;
    outF += (size_t)blockIdx.z * pstride;

    f32x4 acc[4][4];
    for (int i = 0; i < 4; i++)
        for (int j = 0; j < 4; j++)
            acc[i][j] = (f32x4){0.f, 0.f, 0.f, 0.f};

    const int pa0 = 2 * w, pa1 = 2 * w + 1;
    const int srow = lane >> 2, sch = lane & 3;
    const u16* Abase = A + (size_t)tM * K + koff;
    const u16* Bbase = Bt + (size_t)tN * K + koff;
    const size_t r0 = (size_t)(pa0 * 16 + srow) * K + sch * 8;
    const size_t r1 = (size_t)(pa1 * 16 + srow) * K + sch * 8;

    ASYNC16(Abase + r0, lA + pa0 * 512);
    ASYNC16(Abase + r1, lA + pa1 * 512);
    ASYNC16(Bbase + r0, lB + pa0 * 512);
    ASYNC16(Bbase + r1, lB + pa1 * 512);

    const int NT = kchunk / 32;
    for (int kt = 0; kt < NT; kt++) {
        __syncthreads();
        const int cb = (kt & 1) * 4096, nb = 4096 - cb;
        if (kt + 1 < NT) {
            const int k0 = (kt + 1) * 32;
            ASYNC16(Abase + r0 + k0, lA + nb + pa0 * 512);
            ASYNC16(Abase + r1 + k0, lA + nb + pa1 * 512);
            ASYNC16(Bbase + r0 + k0, lB + nb + pa0 * 512);
            ASYNC16(Bbase + r1 + k0, lB + nb + pa1 * 512);
        }
        short8 af[4], bf[4];
        for (int i = 0; i < 4; i++) af[i] = *(const short8*)&lA[cb + (m0 + i * 16 + lane15) * 32 + q * 8];
        for (int j = 0; j < 4; j++) bf[j] = *(const short8*)&lB[cb + (n0 + j * 16 + lane15) * 32 + q * 8];
        for (int i = 0; i < 4; i++)
            for (int j = 0; j < 4; j++)
                acc[i][j] = MFMA16(af[i], bf[j], acc[i][j]);
    }

    if (mode == MODE_F32) {
        // fp32 stores: 16 lanes x 4B = 64B line-granular already
        for (int i = 0; i < 4; i++) {
            const int rb = tM + m0 + i * 16 + q * 4;
            for (int j = 0; j < 4; j++) {
                const int col = tN + n0 + j * 16 + lane15;
                const float bv = (bias && blockIdx.z == 0) ? bias[col] : 0.f;
                for (int r = 0; r < 4; r++)
                    outF[(size_t)(rb + r) * N + col] = acc[i][j][r] + bv;
            }
        }
        return;
    }

    u16* sC = SM;   // 128 x 136
    __syncthreads();
    if (mode == MODE_GELU) {
        for (int i = 0; i < 4; i++) {
            const int rl0 = m0 + i * 16 + q * 4;
            for (int j = 0; j < 4; j++) {
                const int cl = n0 + j * 16 + lane15;
                const float bv = bias[tN + cl];
                for (int r = 0; r < 4; r++) {
                    float v = acc[i][j][r] + bv;
                    v = 0.5f * v * (1.f + erff(v * 0.70710678118f));
                    sC[(rl0 + r) * 136 + cl] = f2b(v);
                }
            }
        }
        __syncthreads();
        for (int t8 = 0; t8 < 8; t8++) {
            const int rl = t8 * 16 + (tid >> 4), cl = (tid & 15) * 8;
            *(u16x8*)&outB[(size_t)(tM + rl) * N + tN + cl] = *(const u16x8*)&sC[rl * 136 + cl];
        }
    } else {  // MODE_VT: stage transposed, write rows of V^T (N==1024)
        for (int i = 0; i < 4; i++) {
            const int rl0 = m0 + i * 16 + q * 4;
            for (int j = 0; j < 4; j++) {
                const int cl = n0 + j * 16 + lane15;
                const float bv = bias[tN + cl];
                for (int r = 0; r < 4; r++)
                    sC[cl * 136 + rl0 + r] = f2b(acc[i][j][r] + bv);
            }
        }
        __syncthreads();
        const int bb = tM >> 11, nbase = tM & 2047;
        for (int t8 = 0; t8 < 8; t8++) {
            const int cl = t8 * 16 + (tid >> 4), rl = (tid & 15) * 8;
            const int colg = tN + cl;
            u16* dst = &outB[((size_t)(bb * 16 + (colg >> 6)) * 64 + (colg & 63)) * 2048 + nbase + rl];
            *(u16x8*)dst = *(const u16x8*)&sC[cl * 136 + rl];
        }
    }
}

// ---------------------------------------------------------------------------
// Flash attention with bf16x3 QK^T (unchanged, passing)
// ---------------------------------------------------------------------------
__global__ __launch_bounds__(256) void attn_fwd(
    const u16* __restrict__ Qhig, const u16* __restrict__ Qlog,
    const u16* __restrict__ Khig, const u16* __restrict__ Klog,
    const u16* __restrict__ Vtg, u16* __restrict__ Og)
{
    __shared__ u16 lQh[2][2048], lQl[2][2048];
    __shared__ u16 lKh[2][1024], lKl[2][1024];
    __shared__ u16 lV[2048];
    __shared__ u16 lP[4][640];

    const int tid = threadIdx.x, w = tid >> 6, lane = tid & 63;
    const int lane15 = lane & 15, q = lane >> 4;
    const int bh = blockIdx.x >> 4, pair = blockIdx.x & 15;
    const int b = bh >> 4, h = bh & 15;

    const size_t xoff = (size_t)b * 2048 * 1024 + h * 64;
    const u16* Qh_ = Qhig + xoff;
    const u16* Ql_ = Qlog + xoff;
    const u16* Kh_ = Khig + xoff;
    const u16* Kl_ = Klog + xoff;
    const u16* Vbh = Vtg + (size_t)bh * 64 * 2048;
    u16* Obh = Og + xoff;

    const int srow = lane >> 2, sch = lane & 3;
    const float NEG = -3.0e38f;

    for (int half = 0; half < 2; half++) {
        const int qb = half ? (31 - pair) : pair;
        const int qrow0 = qb * 64;
        const int ntiles = 2 * qb + 2;

        for (int ii = 0; ii < 4; ii++) {
            const int id = w * 4 + ii;
            const int idq = id & 7, ks = idq >> 2, p = idq & 3;
            const size_t so = (size_t)(qrow0 + p * 16 + srow) * 1024 + ks * 32 + sch * 8;
            if (id < 8) ASYNC16(Qh_ + so, &lQh[ks][p * 512]);
            else        ASYNC16(Ql_ + so, &lQl[ks][p * 512]);
        }

        f32x4 o[4];
        for (int j = 0; j < 4; j++) o[j] = (f32x4){0.f, 0.f, 0.f, 0.f};
        float mrow[4], lrow[4];
        for (int r = 0; r < 4; r++) { mrow[r] = NEG; lrow[r] = 0.f; }
        short8 aqh0 = {}, aqh1 = {}, aql0 = {}, aql1 = {};
        bool first = true;

        for (int t = 0; t < ntiles; t++) {
            const int kk0 = t * 32;
            for (int ii = 0; ii < 3; ii++) {
                const int id = w * 3 + ii;
                if (id < 8) {
                    const int sel = id >> 2, idk = id & 3, ks = idk >> 1, hh = idk & 1;
                    const size_t so = (size_t)(kk0 + hh * 16 + srow) * 1024 + ks * 32 + sch * 8;
                    if (sel == 0) ASYNC16(Kh_ + so, &lKh[ks][hh * 512]);
                    else          ASYNC16(Kl_ + so, &lKl[ks][hh * 512]);
                } else {
                    const int p = id - 8;
                    ASYNC16(Vbh + (size_t)(p * 16 + srow) * 2048 + kk0 + sch * 8, &lV[p * 512]);
                }
            }
            __syncthreads();
            if (first) {
                const int o0 = (w * 16 + lane15) * 32 + q * 8;
                aqh0 = *(const short8*)&lQh[0][o0];
                aqh1 = *(const short8*)&lQh[1][o0];
                aql0 = *(const short8*)&lQl[0][o0];
                aql1 = *(const short8*)&lQl[1][o0];
                first = false;
            }
            f32x4 s[2];
            for (int sub = 0; sub < 2; sub++) {
                const int ko = (sub * 16 + lane15) * 32 + q * 8;
                short8 bkh0 = *(const short8*)&lKh[0][ko];
                short8 bkh1 = *(const short8*)&lKh[1][ko];
                short8 bkl0 = *(const short8*)&lKl[0][ko];
                short8 bkl1 = *(const short8*)&lKl[1][ko];
                f32x4 z = (f32x4){0.f, 0.f, 0.f, 0.f};
                z = MFMA16(aqh0, bkh0, z);
                z = MFMA16(aqh1, bkh1, z);
                z = MFMA16(aqh0, bkl0, z);
                z = MFMA16(aqh1, bkl1, z);
                z = MFMA16(aql0, bkh0, z);
                z = MFMA16(aql1, bkh1, z);
                s[sub] = z;
            }
            const int rbase = qrow0 + w * 16 + q * 4;
            for (int sub = 0; sub < 2; sub++)
                for (int r = 0; r < 4; r++) {
                    const int key = kk0 + sub * 16 + lane15;
                    float sv = s[sub][r] * 8.0f;
                    if (key > rbase + r) sv = NEG;
                    s[sub][r] = sv;
                }
            float mx[4];
            for (int r = 0; r < 4; r++) mx[r] = fmaxf(s[0][r], s[1][r]);
            for (int d = 1; d < 16; d <<= 1)
                for (int r = 0; r < 4; r++) mx[r] = fmaxf(mx[r], __shfl_xor(mx[r], d));
            float alpha[4];
            for (int r = 0; r < 4; r++) {
                const float mnew = fmaxf(mrow[r], mx[r]);
                alpha[r] = __expf(mrow[r] - mnew);
                mrow[r] = mnew;
            }
            float rsum[4] = {0.f, 0.f, 0.f, 0.f};
            for (int sub = 0; sub < 2; sub++)
                for (int r = 0; r < 4; r++) {
                    const float p = __expf(s[sub][r] - mrow[r]);
                    rsum[r] += p;
                    lP[w][(q * 4 + r) * 40 + sub * 16 + lane15] = f2b(p);
                }
            for (int d = 1; d < 16; d <<= 1)
                for (int r = 0; r < 4; r++) rsum[r] += __shfl_xor(rsum[r], d);
            for (int r = 0; r < 4; r++) lrow[r] = lrow[r] * alpha[r] + rsum[r];
            for (int j = 0; j < 4; j++)
                for (int r = 0; r < 4; r++) o[j][r] *= alpha[r];
            short8 ap = *(const short8*)&lP[w][lane15 * 40 + q * 8];
            for (int j = 0; j < 4; j++) {
                short8 bv = *(const short8*)&lV[(j * 16 + lane15) * 32 + q * 8];
                o[j] = MFMA16(ap, bv, o[j]);
            }
            __syncthreads();
        }
        float inv[4];
        for (int r = 0; r < 4; r++) inv[r] = 1.0f / lrow[r];
        for (int j = 0; j < 4; j++)
            for (int r = 0; r < 4; r++)
                Obh[(size_t)(qrow0 + w * 16 + q * 4 + r) * 1024 + j * 16 + lane15] =
                    f2b(o[j][r] * inv[r]);
    }
}

// ---------------------------------------------------------------------------
// y = LN(Xa [+Xb])*g + b + res; res from fp32 or bf16; out bf16 and/or fp32
// ---------------------------------------------------------------------------
__global__ __launch_bounds__(256) void ln_res(
    const float* __restrict__ Xa, const float* __restrict__ Xb,
    const float* __restrict__ resF, const u16* __restrict__ resB,
    const float* __restrict__ g, const float* __restrict__ bb,
    u16* __restrict__ outB, float* __restrict__ outF)
{
    const int w = threadIdx.x >> 6, lane = threadIdx.x & 63;
    const int row = blockIdx.x * 4 + w;
    const size_t rowo = (size_t)row * 1024;
    f32x4 v[4];
    float s = 0.f, ss = 0.f;
    for (int i = 0; i < 4; i++) {
        const int c0 = (i * 64 + lane) * 4;
        v[i] = *(const f32x4*)&Xa[rowo + c0];
        if (Xb) {
            f32x4 v2 = *(const f32x4*)&Xb[rowo + c0];
            for (int k = 0; k < 4; k++) v[i][k] += v2[k];
        }
        for (int k = 0; k < 4; k++) { s += v[i][k]; ss += v[i][k] * v[i][k]; }
    }
    for (int d = 1; d < 64; d <<= 1) { s += __shfl_xor(s, d); ss += __shfl_xor(ss, d); }
    const float mu = s * (1.f / 1024.f);
    const float var = ss * (1.f / 1024.f) - mu * mu;
    const float rstd = rsqrtf(var + 1e-5f);
    for (int i = 0; i < 4; i++) {
        const int c0 = (i * 64 + lane) * 4;
        f32x4 gv = *(const f32x4*)&g[c0];
        f32x4 bv = *(const f32x4*)&bb[c0];
        f32x4 rv;
        if (resF) rv = *(const f32x4*)&resF[rowo + c0];
        else {
            u16x4 rb = *(const u16x4*)&resB[rowo + c0];
            for (int k = 0; k < 4; k++) rv[k] = b2f(rb[k]);
        }
        f32x4 ov;
        for (int k = 0; k < 4; k++)
            ov[k] = (v[i][k] - mu) * rstd * gv[k] + bv[k] + rv[k];
        if (outF) *(f32x4*)&outF[rowo + c0] = ov;
        if (outB) {
            u16x4 ob;
            for (int k = 0; k < 4; k++) ob[k] = f2b(ov[k]);
            *(u16x4*)&outB[rowo + c0] = ob;
        }
    }
}

// ---------------------------------------------------------------------------
extern "C" void kernel_launch(void* const* d_in, const int* in_sizes, int n_in,
                              void* d_out, int out_size, void* d_ws, size_t ws_size,
                              hipStream_t stream)
{
    const float* x   = (const float*)d_in[0];
    const float* Wq  = (const float*)d_in[1];  const float* bq  = (const float*)d_in[2];
    const float* Wk  = (const float*)d_in[3];  const float* bk  = (const float*)d_in[4];
    const float* Wv  = (const float*)d_in[5];  const float* bv  = (const float*)d_in[6];
    const float* Wo  = (const float*)d_in[7];  const float* bo  = (const float*)d_in[8];
    const float* g1  = (const float*)d_in[9];  const float* b1  = (const float*)d_in[10];
    const float* W1  = (const float*)d_in[11]; const float* bm1 = (const float*)d_in[12];
    const float* W2  = (const float*)d_in[13]; const float* bm2 = (const float*)d_in[14];
    const float* g2  = (const float*)d_in[15]; const float* b2  = (const float*)d_in[16];

    // workspace (88 MB peak, lifetime-aliased); MB = 1 MiB
    const size_t MB = (size_t)1 << 20;
    char* ws = (char*)d_ws;
    u16* xhi    = (u16*)(ws + 0 * MB);    // [split .. V/qk]
    u16* xlo    = (u16*)(ws + 8 * MB);    // [split .. qk]
    u16* WqkThi = (u16*)(ws + 16 * MB);   // [.. qk]
    u16* WqkTlo = (u16*)(ws + 20 * MB);   // [.. qk]
    u16* WvT    = (u16*)(ws + 24 * MB);   // [.. V-proj]
    u16* WoT    = (u16*)(ws + 26 * MB);   // [.. o-proj]
    u16* W1T    = (u16*)(ws + 32 * MB);   // [.. FFN1]
    u16* W2T    = (u16*)(ws + 40 * MB);   // [.. FFN2]
    u16* Qhi    = (u16*)(ws + 48 * MB);   // [qk .. attn]
    u16* Qlo    = (u16*)(ws + 56 * MB);
    u16* Khi    = (u16*)(ws + 64 * MB);
    u16* Klo    = (u16*)(ws + 72 * MB);
    u16* Vtb    = (u16*)(ws + 80 * MB);   // [V-proj .. attn]
    u16* aout   = (u16*)(ws + 16 * MB);   // [attn .. o-proj]   (over WqkT)
    float* O1   = (float*)(ws + 48 * MB); // [o-proj .. ln1]    (over Qhi/Qlo)
    float* O2   = (float*)(ws + 64 * MB); //                    (over Khi/Klo)
    u16* x1b    = (u16*)(ws + 80 * MB);   // [ln1 .. ln2]       (over Vtb)
    u16* Hb     = (u16*)(ws + 0 * MB);    // [FFN1 .. FFN2]     (0..32)
    float* H2a  = (float*)(ws + 48 * MB); // [FFN2 .. ln2]      (over O1)
    float* H2b  = (float*)(ws + 64 * MB); //                    (over O2)

    // splits / transposes
    split_f32<<<4096, 256, 0, stream>>>(x, xhi, xlo);
    transpose_split_f32<<<dim3(32, 32), 256, 0, stream>>>(Wq, WqkThi, WqkTlo, 1024, 1024);
    transpose_split_f32<<<dim3(32, 32), 256, 0, stream>>>(Wk, WqkThi + 1024 * 1024,
                                                          WqkTlo + 1024 * 1024, 1024, 1024);
    transpose_f32_bf16<<<dim3(32, 32), 256, 0, stream>>>(Wv, WvT, 1024, 1024);
    transpose_f32_bf16<<<dim3(32, 32), 256, 0, stream>>>(Wo, WoT, 1024, 1024);
    transpose_f32_bf16<<<dim3(128, 32), 256, 0, stream>>>(W1, W1T, 1024, 4096);
    transpose_f32_bf16<<<dim3(32, 128), 256, 0, stream>>>(W2, W2T, 4096, 1024);

    // Q,K projection bf16x3; V projection (V^T layout)
    gemm_qk_x3<<<dim3(16, 32), 256, 0, stream>>>(xhi, xlo, WqkThi, WqkTlo, bq, bk,
                                                 Qhi, Qlo, Khi, Klo);
    gemm_bt<<<dim3(8, 32), 256, 0, stream>>>(xhi, WvT, bv, 4096, 1024, 1024,
                                             MODE_VT, nullptr, Vtb, 0);

    attn_fwd<<<dim3(512), 256, 0, stream>>>(Qhi, Qlo, Khi, Klo, Vtb, aout);

    // out projection, split-K=2 -> fp32 partials O1,O2
    gemm_bt<<<dim3(8, 32, 2), 256, 0, stream>>>(aout, WoT, bo, 4096, 1024, 1024,
                                                MODE_F32, O1, nullptr, (size_t)16 * MB / 4);
    ln_res<<<1024, 256, 0, stream>>>(O1, O2, x, nullptr, g1, b1, x1b, nullptr);

    // FFN
    gemm_bt<<<dim3(32, 32), 256, 0, stream>>>(x1b, W1T, bm1, 4096, 4096, 1024,
                                              MODE_GELU, nullptr, Hb, 0);
    gemm_bt<<<dim3(8, 32, 2), 256, 0, stream>>>(Hb, W2T, bm2, 4096, 1024, 4096,
                                                MODE_F32, H2a, nullptr, (size_t)16 * MB / 4);
    ln_res<<<1024, 256, 0, stream>>>(H2a, H2b, nullptr, x1b, g2, b2, nullptr, (float*)d_out);
}

// Round 7
// 475.549 us; speedup vs baseline: 3.1979x; 1.0733x over previous
//
#include <hip/hip_runtime.h>
#include <stdint.h>

typedef unsigned short u16;
typedef short short8 __attribute__((ext_vector_type(8)));
typedef float f32x4 __attribute__((ext_vector_type(4)));
typedef u16 u16x4 __attribute__((ext_vector_type(4)));
typedef u16 u16x8 __attribute__((ext_vector_type(8)));

#define MODE_F32  0
#define MODE_GELU 2
#define MODE_VT   4

// 8 (bug-faithful sqrt(hd) scale) * log2(e): softmax runs in exp2 domain
#define QSCALE 11.5415603271f

__device__ __forceinline__ float b2f(u16 v) {
    union { uint32_t u; float f; } x; x.u = ((uint32_t)v) << 16; return x.f;
}
__device__ __forceinline__ u16 f2b(float f) {
    union { float f; uint32_t u; } x; x.f = f;
    uint32_t u = x.u;
    return (u16)((u + 0x7FFFu + ((u >> 16) & 1u)) >> 16);   // RNE
}

// async global->LDS, 16B per lane; LDS dest is wave-uniform base + lane*16
#define ASYNC16(gp, lp)                                                        \
    __builtin_amdgcn_global_load_lds(                                          \
        (const __attribute__((address_space(1))) uint32_t*)(const void*)(gp),  \
        (__attribute__((address_space(3))) uint32_t*)(void*)(lp), 16, 0, 0)

#define MFMA16(a, b, c) __builtin_amdgcn_mfma_f32_16x16x32_bf16((a), (b), (c), 0, 0, 0)

// ---------------------------------------------------------------------------
// fp32 -> (hi, lo) bf16 split
// ---------------------------------------------------------------------------
__global__ __launch_bounds__(256) void split_f32(
    const float* __restrict__ in, u16* __restrict__ hi, u16* __restrict__ lo)
{
    const int i = (blockIdx.x * 256 + threadIdx.x) * 4;
    f32x4 v = *(const f32x4*)&in[i];
    u16x4 h, l;
    for (int k = 0; k < 4; k++) {
        h[k] = f2b(v[k]);
        l[k] = f2b(v[k] - b2f(h[k]));
    }
    *(u16x4*)&hi[i] = h;
    *(u16x4*)&lo[i] = l;
}

// fp32 [rows,cols] -> bf16 [cols,rows] transpose+cast
__global__ __launch_bounds__(256) void transpose_f32_bf16(
    const float* __restrict__ in, u16* __restrict__ out, int rows, int cols)
{
    __shared__ float t[32][33];
    const int r0 = blockIdx.y * 32, c0 = blockIdx.x * 32;
    const int tr = threadIdx.x >> 3, tc = (threadIdx.x & 7) * 4;
    f32x4 v = *(const f32x4*)&in[(size_t)(r0 + tr) * cols + c0 + tc];
    for (int i = 0; i < 4; i++) t[tr][tc + i] = v[i];
    __syncthreads();
    u16x4 ov;
    for (int i = 0; i < 4; i++) ov[i] = f2b(t[tc + i][tr]);
    *(u16x4*)&out[(size_t)(c0 + tr) * rows + r0 + tc] = ov;
}

// fp32 [rows,cols] -> bf16 hi/lo [cols,rows] transpose+split
__global__ __launch_bounds__(256) void transpose_split_f32(
    const float* __restrict__ in, u16* __restrict__ hi, u16* __restrict__ lo,
    int rows, int cols)
{
    __shared__ float t[32][33];
    const int r0 = blockIdx.y * 32, c0 = blockIdx.x * 32;
    const int tr = threadIdx.x >> 3, tc = (threadIdx.x & 7) * 4;
    f32x4 v = *(const f32x4*)&in[(size_t)(r0 + tr) * cols + c0 + tc];
    for (int i = 0; i < 4; i++) t[tr][tc + i] = v[i];
    __syncthreads();
    u16x4 hv, lv;
    for (int i = 0; i < 4; i++) {
        const float f = t[tc + i][tr];
        hv[i] = f2b(f);
        lv[i] = f2b(f - b2f(hv[i]));
    }
    const size_t o = (size_t)(c0 + tr) * rows + r0 + tc;
    *(u16x4*)&hi[o] = hv;
    *(u16x4*)&lo[o] = lv;
}

// ---------------------------------------------------------------------------
// QK projection, bf16x3, double-buffered; coalesced hi/lo epilogue via LDS
// Q output is pre-scaled by QSCALE (8*log2e) for the exp2-domain softmax.
// ---------------------------------------------------------------------------
__global__ __launch_bounds__(256) void gemm_qk_x3(
    const u16* __restrict__ Ahi, const u16* __restrict__ Alo,
    const u16* __restrict__ Bhi, const u16* __restrict__ Blo,
    const float* __restrict__ bq, const float* __restrict__ bk,
    u16* __restrict__ Qhi, u16* __restrict__ Qlo,
    u16* __restrict__ Khi, u16* __restrict__ Klo)
{
    const int K = 1024;
    __shared__ __align__(16) u16 SM[32768];   // 64 KB: 4 staged operands x dbuf
    u16* lAh = SM;          u16* lAl = SM + 8192;
    u16* lBh = SM + 16384;  u16* lBl = SM + 24576;

    const int tid = threadIdx.x;
    const int w = tid >> 6, lane = tid & 63;
    const int lane15 = lane & 15, q = lane >> 4;
    const int tM = blockIdx.y * 128, tN = blockIdx.x * 128;
    const int m0 = (w >> 1) * 64, n0 = (w & 1) * 64;

    f32x4 acc[4][4];
    for (int i = 0; i < 4; i++)
        for (int j = 0; j < 4; j++)
            acc[i][j] = (f32x4){0.f, 0.f, 0.f, 0.f};

    const int pa0 = 2 * w, pa1 = 2 * w + 1;
    const int srow = lane >> 2, sch = lane & 3;
    const u16* Ah = Ahi + (size_t)tM * K;
    const u16* Al = Alo + (size_t)tM * K;
    const u16* Bh = Bhi + (size_t)tN * K;
    const u16* Bl = Blo + (size_t)tN * K;
    const size_t r0 = (size_t)(pa0 * 16 + srow) * K + sch * 8;
    const size_t r1 = (size_t)(pa1 * 16 + srow) * K + sch * 8;

    ASYNC16(Ah + r0, lAh + pa0 * 512);  ASYNC16(Ah + r1, lAh + pa1 * 512);
    ASYNC16(Al + r0, lAl + pa0 * 512);  ASYNC16(Al + r1, lAl + pa1 * 512);
    ASYNC16(Bh + r0, lBh + pa0 * 512);  ASYNC16(Bh + r1, lBh + pa1 * 512);
    ASYNC16(Bl + r0, lBl + pa0 * 512);  ASYNC16(Bl + r1, lBl + pa1 * 512);

    const int NT = K / 32;
    for (int kt = 0; kt < NT; kt++) {
        __syncthreads();
        const int cb = (kt & 1) * 4096, nb = 4096 - cb;
        if (kt + 1 < NT) {
            const int k0 = (kt + 1) * 32;
            ASYNC16(Ah + r0 + k0, lAh + nb + pa0 * 512);  ASYNC16(Ah + r1 + k0, lAh + nb + pa1 * 512);
            ASYNC16(Al + r0 + k0, lAl + nb + pa0 * 512);  ASYNC16(Al + r1 + k0, lAl + nb + pa1 * 512);
            ASYNC16(Bh + r0 + k0, lBh + nb + pa0 * 512);  ASYNC16(Bh + r1 + k0, lBh + nb + pa1 * 512);
            ASYNC16(Bl + r0 + k0, lBl + nb + pa0 * 512);  ASYNC16(Bl + r1 + k0, lBl + nb + pa1 * 512);
        }
        short8 afh[4], afl[4], bfh[4], bfl[4];
        for (int i = 0; i < 4; i++) {
            const int o = cb + (m0 + i * 16 + lane15) * 32 + q * 8;
            afh[i] = *(const short8*)&lAh[o];
            afl[i] = *(const short8*)&lAl[o];
        }
        for (int j = 0; j < 4; j++) {
            const int o = cb + (n0 + j * 16 + lane15) * 32 + q * 8;
            bfh[j] = *(const short8*)&lBh[o];
            bfl[j] = *(const short8*)&lBl[o];
        }
        for (int i = 0; i < 4; i++)
            for (int j = 0; j < 4; j++) {
                acc[i][j] = MFMA16(afh[i], bfh[j], acc[i][j]);
                acc[i][j] = MFMA16(afh[i], bfl[j], acc[i][j]);
                acc[i][j] = MFMA16(afl[i], bfh[j], acc[i][j]);
            }
    }

    // epilogue: block writes Q (tN<1024, scaled) or K; hi+lo passes through LDS
    const bool isQ = (tN < 1024);
    u16* dhi = isQ ? Qhi : Khi;
    u16* dlo = isQ ? Qlo : Klo;
    const int cN = isQ ? tN : (tN - 1024);
    const float scl = isQ ? QSCALE : 1.0f;
    u16* sC = SM;   // 128 x 136
    for (int pass = 0; pass < 2; pass++) {
        __syncthreads();
        for (int i = 0; i < 4; i++) {
            const int rl0 = m0 + i * 16 + q * 4;
            for (int j = 0; j < 4; j++) {
                const int cl = n0 + j * 16 + lane15;
                const float bv = isQ ? bq[cN + cl] : bk[cN + cl];
                for (int r = 0; r < 4; r++) {
                    const float v = (acc[i][j][r] + bv) * scl;
                    const u16 hv = f2b(v);
                    sC[(rl0 + r) * 136 + cl] = pass == 0 ? hv : f2b(v - b2f(hv));
                }
            }
        }
        __syncthreads();
        u16* dst = pass == 0 ? dhi : dlo;
        for (int t8 = 0; t8 < 8; t8++) {
            const int rl = t8 * 16 + (tid >> 4), cl = (tid & 15) * 8;
            *(u16x8*)&dst[(size_t)(tM + rl) * 1024 + cN + cl] = *(const u16x8*)&sC[rl * 136 + cl];
        }
    }
}

// ---------------------------------------------------------------------------
// C = A[M,K] * Bt[N,K]^T + bias; dbuf K-loop; optional split-K via gridDim.z
// ---------------------------------------------------------------------------
__global__ __launch_bounds__(256) void gemm_bt(
    const u16* __restrict__ A, const u16* __restrict__ Bt, const float* __restrict__ bias,
    int M, int N, int K, int mode,
    float* __restrict__ outF, u16* __restrict__ outB, size_t pstride)
{
    __shared__ __align__(16) u16 SM[17408];
    u16* lA = SM;
    u16* lB = SM + 8192;

    const int tid = threadIdx.x;
    const int w = tid >> 6, lane = tid & 63;
    const int lane15 = lane & 15, q = lane >> 4;
    const int tM = blockIdx.y * 128, tN = blockIdx.x * 128;
    const int m0 = (w >> 1) * 64, n0 = (w & 1) * 64;

    const int kchunk = K / gridDim.z;
    const int koff = blockIdx.z * kchunk;
    outF += (size_t)blockIdx.z * pstride;

    f32x4 acc[4][4];
    for (int i = 0; i < 4; i++)
        for (int j = 0; j < 4; j++)
            acc[i][j] = (f32x4){0.f, 0.f, 0.f, 0.f};

    const int pa0 = 2 * w, pa1 = 2 * w + 1;
    const int srow = lane >> 2, sch = lane & 3;
    const u16* Abase = A + (size_t)tM * K + koff;
    const u16* Bbase = Bt + (size_t)tN * K + koff;
    const size_t r0 = (size_t)(pa0 * 16 + srow) * K + sch * 8;
    const size_t r1 = (size_t)(pa1 * 16 + srow) * K + sch * 8;

    ASYNC16(Abase + r0, lA + pa0 * 512);
    ASYNC16(Abase + r1, lA + pa1 * 512);
    ASYNC16(Bbase + r0, lB + pa0 * 512);
    ASYNC16(Bbase + r1, lB + pa1 * 512);

    const int NT = kchunk / 32;
    for (int kt = 0; kt < NT; kt++) {
        __syncthreads();
        const int cb = (kt & 1) * 4096, nb = 4096 - cb;
        if (kt + 1 < NT) {
            const int k0 = (kt + 1) * 32;
            ASYNC16(Abase + r0 + k0, lA + nb + pa0 * 512);
            ASYNC16(Abase + r1 + k0, lA + nb + pa1 * 512);
            ASYNC16(Bbase + r0 + k0, lB + nb + pa0 * 512);
            ASYNC16(Bbase + r1 + k0, lB + nb + pa1 * 512);
        }
        short8 af[4], bf[4];
        for (int i = 0; i < 4; i++) af[i] = *(const short8*)&lA[cb + (m0 + i * 16 + lane15) * 32 + q * 8];
        for (int j = 0; j < 4; j++) bf[j] = *(const short8*)&lB[cb + (n0 + j * 16 + lane15) * 32 + q * 8];
        for (int i = 0; i < 4; i++)
            for (int j = 0; j < 4; j++)
                acc[i][j] = MFMA16(af[i], bf[j], acc[i][j]);
    }

    if (mode == MODE_F32) {
        for (int i = 0; i < 4; i++) {
            const int rb = tM + m0 + i * 16 + q * 4;
            for (int j = 0; j < 4; j++) {
                const int col = tN + n0 + j * 16 + lane15;
                const float bv = (bias && blockIdx.z == 0) ? bias[col] : 0.f;
                for (int r = 0; r < 4; r++)
                    outF[(size_t)(rb + r) * N + col] = acc[i][j][r] + bv;
            }
        }
        return;
    }

    u16* sC = SM;   // 128 x 136
    __syncthreads();
    if (mode == MODE_GELU) {
        for (int i = 0; i < 4; i++) {
            const int rl0 = m0 + i * 16 + q * 4;
            for (int j = 0; j < 4; j++) {
                const int cl = n0 + j * 16 + lane15;
                const float bv = bias[tN + cl];
                for (int r = 0; r < 4; r++) {
                    float v = acc[i][j][r] + bv;
                    v = 0.5f * v * (1.f + erff(v * 0.70710678118f));
                    sC[(rl0 + r) * 136 + cl] = f2b(v);
                }
            }
        }
        __syncthreads();
        for (int t8 = 0; t8 < 8; t8++) {
            const int rl = t8 * 16 + (tid >> 4), cl = (tid & 15) * 8;
            *(u16x8*)&outB[(size_t)(tM + rl) * N + tN + cl] = *(const u16x8*)&sC[rl * 136 + cl];
        }
    } else {  // MODE_VT
        for (int i = 0; i < 4; i++) {
            const int rl0 = m0 + i * 16 + q * 4;
            for (int j = 0; j < 4; j++) {
                const int cl = n0 + j * 16 + lane15;
                const float bv = bias[tN + cl];
                for (int r = 0; r < 4; r++)
                    sC[cl * 136 + rl0 + r] = f2b(acc[i][j][r] + bv);
            }
        }
        __syncthreads();
        const int bb = tM >> 11, nbase = tM & 2047;
        for (int t8 = 0; t8 < 8; t8++) {
            const int cl = t8 * 16 + (tid >> 4), rl = (tid & 15) * 8;
            const int colg = tN + cl;
            u16* dst = &outB[((size_t)(bb * 16 + (colg >> 6)) * 64 + (colg & 63)) * 2048 + nbase + rl];
            *(u16x8*)dst = *(const u16x8*)&sC[cl * 136 + rl];
        }
    }
}

// ---------------------------------------------------------------------------
// Flash attention, bf16x3 QK^T (Q pre-scaled by 8*log2e -> exp2 softmax)
// grid 1024: bh = blk&31 (XCD-clustered: blk%8 == bh%8), qb = 31-(blk>>5)
// double-buffered K/V staging, one barrier per 32-key tile
// ---------------------------------------------------------------------------
__global__ __launch_bounds__(256) void attn_fwd(
    const u16* __restrict__ Qhig, const u16* __restrict__ Qlog,
    const u16* __restrict__ Khig, const u16* __restrict__ Klog,
    const u16* __restrict__ Vtg, u16* __restrict__ Og)
{
    __shared__ u16 lQh[2][2048], lQl[2][2048];        // [d-half][64 rows x 32]
    __shared__ u16 lKh[2][2][1024], lKl[2][2][1024];  // [buf][d-half][32 keys x 32]
    __shared__ u16 lV[2][2048];                       // [buf][64 d x 32 keys]
    __shared__ u16 lP[4][640];                        // per-wave P, stride 40

    const int tid = threadIdx.x, w = tid >> 6, lane = tid & 63;
    const int lane15 = lane & 15, q = lane >> 4;
    const int bh = blockIdx.x & 31;          // same bh -> same XCD (mod 8)
    const int qb = 31 - (blockIdx.x >> 5);   // heaviest q-blocks first
    const int b = bh >> 4, h = bh & 15;

    const size_t xoff = (size_t)b * 2048 * 1024 + h * 64;
    const u16* Qh_ = Qhig + xoff;
    const u16* Ql_ = Qlog + xoff;
    const u16* Kh_ = Khig + xoff;
    const u16* Kl_ = Klog + xoff;
    const u16* Vbh = Vtg + (size_t)bh * 64 * 2048;
    u16* Obh = Og + xoff;

    const int srow = lane >> 2, sch = lane & 3;
    const float NEG = -3.0e38f;
    const int qrow0 = qb * 64;
    const int ntiles = 2 * qb + 2;

    // prologue: stage Q hi+lo (16 chunks, 4/wave) and K/V tile 0 (12 chunks, 3/wave)
    for (int ii = 0; ii < 4; ii++) {
        const int id = w * 4 + ii;
        const int idq = id & 7, ks = idq >> 2, p = idq & 3;
        const size_t so = (size_t)(qrow0 + p * 16 + srow) * 1024 + ks * 32 + sch * 8;
        if (id < 8) ASYNC16(Qh_ + so, &lQh[ks][p * 512]);
        else        ASYNC16(Ql_ + so, &lQl[ks][p * 512]);
    }
    for (int ii = 0; ii < 3; ii++) {
        const int id = w * 3 + ii;
        if (id < 8) {
            const int sel = id >> 2, idk = id & 3, ks = idk >> 1, hh = idk & 1;
            const size_t so = (size_t)(hh * 16 + srow) * 1024 + ks * 32 + sch * 8;
            if (sel == 0) ASYNC16(Kh_ + so, &lKh[0][ks][hh * 512]);
            else          ASYNC16(Kl_ + so, &lKl[0][ks][hh * 512]);
        } else {
            const int p = id - 8;
            ASYNC16(Vbh + (size_t)(p * 16 + srow) * 2048 + sch * 8, &lV[0][p * 512]);
        }
    }

    f32x4 o[4];
    for (int j = 0; j < 4; j++) o[j] = (f32x4){0.f, 0.f, 0.f, 0.f};
    float mrow[4], lrow[4];
    for (int r = 0; r < 4; r++) { mrow[r] = NEG; lrow[r] = 0.f; }
    short8 aqh0 = {}, aqh1 = {}, aql0 = {}, aql1 = {};
    bool first = true;

    for (int t = 0; t < ntiles; t++) {
        __syncthreads();   // tile t + (Q on t=0) resident; buf t&1 readable
        const int cur = t & 1, nxt = cur ^ 1;
        if (t + 1 < ntiles) {   // prefetch tile t+1 into other buffer
            const int kk1 = (t + 1) * 32;
            for (int ii = 0; ii < 3; ii++) {
                const int id = w * 3 + ii;
                if (id < 8) {
                    const int sel = id >> 2, idk = id & 3, ks = idk >> 1, hh = idk & 1;
                    const size_t so = (size_t)(kk1 + hh * 16 + srow) * 1024 + ks * 32 + sch * 8;
                    if (sel == 0) ASYNC16(Kh_ + so, &lKh[nxt][ks][hh * 512]);
                    else          ASYNC16(Kl_ + so, &lKl[nxt][ks][hh * 512]);
                } else {
                    const int p = id - 8;
                    ASYNC16(Vbh + (size_t)(p * 16 + srow) * 2048 + kk1 + sch * 8,
                            &lV[nxt][p * 512]);
                }
            }
        }
        if (first) {
            const int o0 = (w * 16 + lane15) * 32 + q * 8;
            aqh0 = *(const short8*)&lQh[0][o0];
            aqh1 = *(const short8*)&lQh[1][o0];
            aql0 = *(const short8*)&lQl[0][o0];
            aql1 = *(const short8*)&lQl[1][o0];
            first = false;
        }
        const int kk0 = t * 32;
        // S = (Qhi+Qlo)(Khi+Klo)^T (lo*lo dropped); logits already * 8*log2e
        f32x4 s[2];
        for (int sub = 0; sub < 2; sub++) {
            const int ko = (sub * 16 + lane15) * 32 + q * 8;
            short8 bkh0 = *(const short8*)&lKh[cur][0][ko];
            short8 bkh1 = *(const short8*)&lKh[cur][1][ko];
            short8 bkl0 = *(const short8*)&lKl[cur][0][ko];
            short8 bkl1 = *(const short8*)&lKl[cur][1][ko];
            f32x4 z = (f32x4){0.f, 0.f, 0.f, 0.f};
            z = MFMA16(aqh0, bkh0, z);
            z = MFMA16(aqh1, bkh1, z);
            z = MFMA16(aqh0, bkl0, z);
            z = MFMA16(aqh1, bkl1, z);
            z = MFMA16(aql0, bkh0, z);
            z = MFMA16(aql1, bkh1, z);
            s[sub] = z;
        }
        // causal mask
        const int rbase = qrow0 + w * 16 + q * 4;
        for (int sub = 0; sub < 2; sub++)
            for (int r = 0; r < 4; r++) {
                const int key = kk0 + sub * 16 + lane15;
                if (key > rbase + r) s[sub][r] = NEG;
            }
        // online softmax (exp2 domain; rows live in 16-lane groups)
        float mx[4];
        for (int r = 0; r < 4; r++) mx[r] = fmaxf(s[0][r], s[1][r]);
        for (int d = 1; d < 16; d <<= 1)
            for (int r = 0; r < 4; r++) mx[r] = fmaxf(mx[r], __shfl_xor(mx[r], d));
        float alpha[4];
        for (int r = 0; r < 4; r++) {
            const float mnew = fmaxf(mrow[r], mx[r]);
            alpha[r] = __builtin_exp2f(mrow[r] - mnew);
            mrow[r] = mnew;
        }
        float rsum[4] = {0.f, 0.f, 0.f, 0.f};
        for (int sub = 0; sub < 2; sub++)
            for (int r = 0; r < 4; r++) {
                const float p = __builtin_exp2f(s[sub][r] - mrow[r]);
                rsum[r] += p;
                lP[w][(q * 4 + r) * 40 + sub * 16 + lane15] = f2b(p);
            }
        for (int d = 1; d < 16; d <<= 1)
            for (int r = 0; r < 4; r++) rsum[r] += __shfl_xor(rsum[r], d);
        for (int r = 0; r < 4; r++) lrow[r] = lrow[r] * alpha[r] + rsum[r];
        for (int j = 0; j < 4; j++)
            for (int r = 0; r < 4; r++) o[j][r] *= alpha[r];
        // O += P V  (P via per-wave LDS round-trip into A-layout)
        short8 ap = *(const short8*)&lP[w][lane15 * 40 + q * 8];
        for (int j = 0; j < 4; j++) {
            short8 bv = *(const short8*)&lV[cur][(j * 16 + lane15) * 32 + q * 8];
            o[j] = MFMA16(ap, bv, o[j]);
        }
    }
    // normalize + write
    float inv[4];
    for (int r = 0; r < 4; r++) inv[r] = 1.0f / lrow[r];
    for (int j = 0; j < 4; j++)
        for (int r = 0; r < 4; r++)
            Obh[(size_t)(qrow0 + w * 16 + q * 4 + r) * 1024 + j * 16 + lane15] =
                f2b(o[j][r] * inv[r]);
}

// ---------------------------------------------------------------------------
// y = LN(Xa [+Xb])*g + b + res; res fp32 or bf16; out bf16 and/or fp32
// ---------------------------------------------------------------------------
__global__ __launch_bounds__(256) void ln_res(
    const float* __restrict__ Xa, const float* __restrict__ Xb,
    const float* __restrict__ resF, const u16* __restrict__ resB,
    const float* __restrict__ g, const float* __restrict__ bb,
    u16* __restrict__ outB, float* __restrict__ outF)
{
    const int w = threadIdx.x >> 6, lane = threadIdx.x & 63;
    const int row = blockIdx.x * 4 + w;
    const size_t rowo = (size_t)row * 1024;
    f32x4 v[4];
    float s = 0.f, ss = 0.f;
    for (int i = 0; i < 4; i++) {
        const int c0 = (i * 64 + lane) * 4;
        v[i] = *(const f32x4*)&Xa[rowo + c0];
        if (Xb) {
            f32x4 v2 = *(const f32x4*)&Xb[rowo + c0];
            for (int k = 0; k < 4; k++) v[i][k] += v2[k];
        }
        for (int k = 0; k < 4; k++) { s += v[i][k]; ss += v[i][k] * v[i][k]; }
    }
    for (int d = 1; d < 64; d <<= 1) { s += __shfl_xor(s, d); ss += __shfl_xor(ss, d); }
    const float mu = s * (1.f / 1024.f);
    const float var = ss * (1.f / 1024.f) - mu * mu;
    const float rstd = rsqrtf(var + 1e-5f);
    for (int i = 0; i < 4; i++) {
        const int c0 = (i * 64 + lane) * 4;
        f32x4 gv = *(const f32x4*)&g[c0];
        f32x4 bv = *(const f32x4*)&bb[c0];
        f32x4 rv;
        if (resF) rv = *(const f32x4*)&resF[rowo + c0];
        else {
            u16x4 rb = *(const u16x4*)&resB[rowo + c0];
            for (int k = 0; k < 4; k++) rv[k] = b2f(rb[k]);
        }
        f32x4 ov;
        for (int k = 0; k < 4; k++)
            ov[k] = (v[i][k] - mu) * rstd * gv[k] + bv[k] + rv[k];
        if (outF) *(f32x4*)&outF[rowo + c0] = ov;
        if (outB) {
            u16x4 ob;
            for (int k = 0; k < 4; k++) ob[k] = f2b(ov[k]);
            *(u16x4*)&outB[rowo + c0] = ob;
        }
    }
}

// ---------------------------------------------------------------------------
extern "C" void kernel_launch(void* const* d_in, const int* in_sizes, int n_in,
                              void* d_out, int out_size, void* d_ws, size_t ws_size,
                              hipStream_t stream)
{
    const float* x   = (const float*)d_in[0];
    const float* Wq  = (const float*)d_in[1];  const float* bq  = (const float*)d_in[2];
    const float* Wk  = (const float*)d_in[3];  const float* bk  = (const float*)d_in[4];
    const float* Wv  = (const float*)d_in[5];  const float* bv  = (const float*)d_in[6];
    const float* Wo  = (const float*)d_in[7];  const float* bo  = (const float*)d_in[8];
    const float* g1  = (const float*)d_in[9];  const float* b1  = (const float*)d_in[10];
    const float* W1  = (const float*)d_in[11]; const float* bm1 = (const float*)d_in[12];
    const float* W2  = (const float*)d_in[13]; const float* bm2 = (const float*)d_in[14];
    const float* g2  = (const float*)d_in[15]; const float* b2  = (const float*)d_in[16];

    // workspace (88 MB peak, lifetime-aliased); MB = 1 MiB
    const size_t MB = (size_t)1 << 20;
    char* ws = (char*)d_ws;
    u16* xhi    = (u16*)(ws + 0 * MB);
    u16* xlo    = (u16*)(ws + 8 * MB);
    u16* WqkThi = (u16*)(ws + 16 * MB);
    u16* WqkTlo = (u16*)(ws + 20 * MB);
    u16* WvT    = (u16*)(ws + 24 * MB);
    u16* WoT    = (u16*)(ws + 26 * MB);
    u16* W1T    = (u16*)(ws + 32 * MB);
    u16* W2T    = (u16*)(ws + 40 * MB);
    u16* Qhi    = (u16*)(ws + 48 * MB);
    u16* Qlo    = (u16*)(ws + 56 * MB);
    u16* Khi    = (u16*)(ws + 64 * MB);
    u16* Klo    = (u16*)(ws + 72 * MB);
    u16* Vtb    = (u16*)(ws + 80 * MB);
    u16* aout   = (u16*)(ws + 16 * MB);
    float* O1   = (float*)(ws + 48 * MB);
    float* O2   = (float*)(ws + 64 * MB);
    u16* x1b    = (u16*)(ws + 80 * MB);
    u16* Hb     = (u16*)(ws + 0 * MB);
    float* H2a  = (float*)(ws + 48 * MB);
    float* H2b  = (float*)(ws + 64 * MB);

    split_f32<<<4096, 256, 0, stream>>>(x, xhi, xlo);
    transpose_split_f32<<<dim3(32, 32), 256, 0, stream>>>(Wq, WqkThi, WqkTlo, 1024, 1024);
    transpose_split_f32<<<dim3(32, 32), 256, 0, stream>>>(Wk, WqkThi + 1024 * 1024,
                                                          WqkTlo + 1024 * 1024, 1024, 1024);
    transpose_f32_bf16<<<dim3(32, 32), 256, 0, stream>>>(Wv, WvT, 1024, 1024);
    transpose_f32_bf16<<<dim3(32, 32), 256, 0, stream>>>(Wo, WoT, 1024, 1024);
    transpose_f32_bf16<<<dim3(128, 32), 256, 0, stream>>>(W1, W1T, 1024, 4096);
    transpose_f32_bf16<<<dim3(32, 128), 256, 0, stream>>>(W2, W2T, 4096, 1024);

    gemm_qk_x3<<<dim3(16, 32), 256, 0, stream>>>(xhi, xlo, WqkThi, WqkTlo, bq, bk,
                                                 Qhi, Qlo, Khi, Klo);
    gemm_bt<<<dim3(8, 32), 256, 0, stream>>>(xhi, WvT, bv, 4096, 1024, 1024,
                                             MODE_VT, nullptr, Vtb, 0);

    attn_fwd<<<dim3(1024), 256, 0, stream>>>(Qhi, Qlo, Khi, Klo, Vtb, aout);

    gemm_bt<<<dim3(8, 32, 2), 256, 0, stream>>>(aout, WoT, bo, 4096, 1024, 1024,
                                                MODE_F32, O1, nullptr, (size_t)16 * MB / 4);
    ln_res<<<1024, 256, 0, stream>>>(O1, O2, x, nullptr, g1, b1, x1b, nullptr);

    gemm_bt<<<dim3(32, 32), 256, 0, stream>>>(x1b, W1T, bm1, 4096, 4096, 1024,
                                              MODE_GELU, nullptr, Hb, 0);
    gemm_bt<<<dim3(8, 32, 2), 256, 0, stream>>>(Hb, W2T, bm2, 4096, 1024, 4096,
                                                MODE_F32, H2a, nullptr, (size_t)16 * MB / 4);
    ln_res<<<1024, 256, 0, stream>>>(H2a, H2b, nullptr, x1b, g2, b2, nullptr, (float*)d_out);
}

// Round 8
// 472.008 us; speedup vs baseline: 3.2219x; 1.0075x over previous
//
#include <hip/hip_runtime.h>
#include <stdint.h>

typedef unsigned short u16;
typedef short short8 __attribute__((ext_vector_type(8)));
typedef float f32x4 __attribute__((ext_vector_type(4)));
typedef u16 u16x4 __attribute__((ext_vector_type(4)));
typedef u16 u16x8 __attribute__((ext_vector_type(8)));

#define MODE_F32  0
#define MODE_GELU 2
#define MODE_VT   4

// 8 (bug-faithful sqrt(hd) scale) * log2(e): softmax runs in exp2 domain
#define QSCALE 11.5415603271f

__device__ __forceinline__ float b2f(u16 v) {
    union { uint32_t u; float f; } x; x.u = ((uint32_t)v) << 16; return x.f;
}
__device__ __forceinline__ u16 f2b(float f) {
    union { float f; uint32_t u; } x; x.f = f;
    uint32_t u = x.u;
    return (u16)((u + 0x7FFFu + ((u >> 16) & 1u)) >> 16);   // RNE
}
__device__ __forceinline__ u16 f2b_trunc(float f) {        // cheap: P only
    union { float f; uint32_t u; } x; x.f = f;
    return (u16)(x.u >> 16);
}

// async global->LDS, 16B per lane; LDS dest is wave-uniform base + lane*16
#define ASYNC16(gp, lp)                                                        \
    __builtin_amdgcn_global_load_lds(                                          \
        (const __attribute__((address_space(1))) uint32_t*)(const void*)(gp),  \
        (__attribute__((address_space(3))) uint32_t*)(void*)(lp), 16, 0, 0)

#define MFMA16(a, b, c) __builtin_amdgcn_mfma_f32_16x16x32_bf16((a), (b), (c), 0, 0, 0)

// ---------------------------------------------------------------------------
// fp32 -> (hi, lo) bf16 split
// ---------------------------------------------------------------------------
__global__ __launch_bounds__(256) void split_f32(
    const float* __restrict__ in, u16* __restrict__ hi, u16* __restrict__ lo)
{
    const int i = (blockIdx.x * 256 + threadIdx.x) * 4;
    f32x4 v = *(const f32x4*)&in[i];
    u16x4 h, l;
    for (int k = 0; k < 4; k++) {
        h[k] = f2b(v[k]);
        l[k] = f2b(v[k] - b2f(h[k]));
    }
    *(u16x4*)&hi[i] = h;
    *(u16x4*)&lo[i] = l;
}

// fp32 [rows,cols] -> bf16 [cols,rows] transpose+cast; z picks (inA,outA)/(inB,outB)
__global__ __launch_bounds__(256) void transpose_f32_bf16(
    const float* __restrict__ inA, u16* __restrict__ outA,
    const float* __restrict__ inB, u16* __restrict__ outB, int rows, int cols)
{
    const float* in = blockIdx.z ? inB : inA;
    u16* out = blockIdx.z ? outB : outA;
    __shared__ float t[32][33];
    const int r0 = blockIdx.y * 32, c0 = blockIdx.x * 32;
    const int tr = threadIdx.x >> 3, tc = (threadIdx.x & 7) * 4;
    f32x4 v = *(const f32x4*)&in[(size_t)(r0 + tr) * cols + c0 + tc];
    for (int i = 0; i < 4; i++) t[tr][tc + i] = v[i];
    __syncthreads();
    u16x4 ov;
    for (int i = 0; i < 4; i++) ov[i] = f2b(t[tc + i][tr]);
    *(u16x4*)&out[(size_t)(c0 + tr) * rows + r0 + tc] = ov;
}

// fp32 [rows,cols] -> bf16 hi/lo [cols,rows] transpose+split; z picks A/B set
__global__ __launch_bounds__(256) void transpose_split_f32(
    const float* __restrict__ inA, u16* __restrict__ hiA, u16* __restrict__ loA,
    const float* __restrict__ inB, u16* __restrict__ hiB, u16* __restrict__ loB,
    int rows, int cols)
{
    const float* in = blockIdx.z ? inB : inA;
    u16* hi = blockIdx.z ? hiB : hiA;
    u16* lo = blockIdx.z ? loB : loA;
    __shared__ float t[32][33];
    const int r0 = blockIdx.y * 32, c0 = blockIdx.x * 32;
    const int tr = threadIdx.x >> 3, tc = (threadIdx.x & 7) * 4;
    f32x4 v = *(const f32x4*)&in[(size_t)(r0 + tr) * cols + c0 + tc];
    for (int i = 0; i < 4; i++) t[tr][tc + i] = v[i];
    __syncthreads();
    u16x4 hv, lv;
    for (int i = 0; i < 4; i++) {
        const float f = t[tc + i][tr];
        hv[i] = f2b(f);
        lv[i] = f2b(f - b2f(hv[i]));
    }
    const size_t o = (size_t)(c0 + tr) * rows + r0 + tc;
    *(u16x4*)&hi[o] = hv;
    *(u16x4*)&lo[o] = lv;
}

// ---------------------------------------------------------------------------
// QK projection, bf16x3, double-buffered; coalesced hi/lo epilogue via LDS
// Q output is pre-scaled by QSCALE (8*log2e) for the exp2-domain softmax.
// ---------------------------------------------------------------------------
__global__ __launch_bounds__(256) void gemm_qk_x3(
    const u16* __restrict__ Ahi, const u16* __restrict__ Alo,
    const u16* __restrict__ Bhi, const u16* __restrict__ Blo,
    const float* __restrict__ bq, const float* __restrict__ bk,
    u16* __restrict__ Qhi, u16* __restrict__ Qlo,
    u16* __restrict__ Khi, u16* __restrict__ Klo)
{
    const int K = 1024;
    __shared__ __align__(16) u16 SM[32768];   // 64 KB: 4 staged operands x dbuf
    u16* lAh = SM;          u16* lAl = SM + 8192;
    u16* lBh = SM + 16384;  u16* lBl = SM + 24576;

    const int tid = threadIdx.x;
    const int w = tid >> 6, lane = tid & 63;
    const int lane15 = lane & 15, q = lane >> 4;
    const int tM = blockIdx.y * 128, tN = blockIdx.x * 128;
    const int m0 = (w >> 1) * 64, n0 = (w & 1) * 64;

    f32x4 acc[4][4];
    for (int i = 0; i < 4; i++)
        for (int j = 0; j < 4; j++)
            acc[i][j] = (f32x4){0.f, 0.f, 0.f, 0.f};

    const int pa0 = 2 * w, pa1 = 2 * w + 1;
    const int srow = lane >> 2, sch = lane & 3;
    const u16* Ah = Ahi + (size_t)tM * K;
    const u16* Al = Alo + (size_t)tM * K;
    const u16* Bh = Bhi + (size_t)tN * K;
    const u16* Bl = Blo + (size_t)tN * K;
    const size_t r0 = (size_t)(pa0 * 16 + srow) * K + sch * 8;
    const size_t r1 = (size_t)(pa1 * 16 + srow) * K + sch * 8;

    ASYNC16(Ah + r0, lAh + pa0 * 512);  ASYNC16(Ah + r1, lAh + pa1 * 512);
    ASYNC16(Al + r0, lAl + pa0 * 512);  ASYNC16(Al + r1, lAl + pa1 * 512);
    ASYNC16(Bh + r0, lBh + pa0 * 512);  ASYNC16(Bh + r1, lBh + pa1 * 512);
    ASYNC16(Bl + r0, lBl + pa0 * 512);  ASYNC16(Bl + r1, lBl + pa1 * 512);

    const int NT = K / 32;
    for (int kt = 0; kt < NT; kt++) {
        __syncthreads();
        const int cb = (kt & 1) * 4096, nb = 4096 - cb;
        if (kt + 1 < NT) {
            const int k0 = (kt + 1) * 32;
            ASYNC16(Ah + r0 + k0, lAh + nb + pa0 * 512);  ASYNC16(Ah + r1 + k0, lAh + nb + pa1 * 512);
            ASYNC16(Al + r0 + k0, lAl + nb + pa0 * 512);  ASYNC16(Al + r1 + k0, lAl + nb + pa1 * 512);
            ASYNC16(Bh + r0 + k0, lBh + nb + pa0 * 512);  ASYNC16(Bh + r1 + k0, lBh + nb + pa1 * 512);
            ASYNC16(Bl + r0 + k0, lBl + nb + pa0 * 512);  ASYNC16(Bl + r1 + k0, lBl + nb + pa1 * 512);
        }
        short8 afh[4], afl[4], bfh[4], bfl[4];
        for (int i = 0; i < 4; i++) {
            const int o = cb + (m0 + i * 16 + lane15) * 32 + q * 8;
            afh[i] = *(const short8*)&lAh[o];
            afl[i] = *(const short8*)&lAl[o];
        }
        for (int j = 0; j < 4; j++) {
            const int o = cb + (n0 + j * 16 + lane15) * 32 + q * 8;
            bfh[j] = *(const short8*)&lBh[o];
            bfl[j] = *(const short8*)&lBl[o];
        }
        for (int i = 0; i < 4; i++)
            for (int j = 0; j < 4; j++) {
                acc[i][j] = MFMA16(afh[i], bfh[j], acc[i][j]);
                acc[i][j] = MFMA16(afh[i], bfl[j], acc[i][j]);
                acc[i][j] = MFMA16(afl[i], bfh[j], acc[i][j]);
            }
    }

    // epilogue: block writes Q (tN<1024, scaled) or K; hi+lo passes through LDS
    const bool isQ = (tN < 1024);
    u16* dhi = isQ ? Qhi : Khi;
    u16* dlo = isQ ? Qlo : Klo;
    const int cN = isQ ? tN : (tN - 1024);
    const float scl = isQ ? QSCALE : 1.0f;
    u16* sC = SM;   // 128 x 136
    for (int pass = 0; pass < 2; pass++) {
        __syncthreads();
        for (int i = 0; i < 4; i++) {
            const int rl0 = m0 + i * 16 + q * 4;
            for (int j = 0; j < 4; j++) {
                const int cl = n0 + j * 16 + lane15;
                const float bv = isQ ? bq[cN + cl] : bk[cN + cl];
                for (int r = 0; r < 4; r++) {
                    const float v = (acc[i][j][r] + bv) * scl;
                    const u16 hv = f2b(v);
                    sC[(rl0 + r) * 136 + cl] = pass == 0 ? hv : f2b(v - b2f(hv));
                }
            }
        }
        __syncthreads();
        u16* dst = pass == 0 ? dhi : dlo;
        for (int t8 = 0; t8 < 8; t8++) {
            const int rl = t8 * 16 + (tid >> 4), cl = (tid & 15) * 8;
            *(u16x8*)&dst[(size_t)(tM + rl) * 1024 + cN + cl] = *(const u16x8*)&sC[rl * 136 + cl];
        }
    }
}

// ---------------------------------------------------------------------------
// C = A[M,K] * Bt[N,K]^T + bias; dbuf K-loop; optional split-K via gridDim.z
// ---------------------------------------------------------------------------
__global__ __launch_bounds__(256) void gemm_bt(
    const u16* __restrict__ A, const u16* __restrict__ Bt, const float* __restrict__ bias,
    int M, int N, int K, int mode,
    float* __restrict__ outF, u16* __restrict__ outB, size_t pstride)
{
    __shared__ __align__(16) u16 SM[17408];
    u16* lA = SM;
    u16* lB = SM + 8192;

    const int tid = threadIdx.x;
    const int w = tid >> 6, lane = tid & 63;
    const int lane15 = lane & 15, q = lane >> 4;
    const int tM = blockIdx.y * 128, tN = blockIdx.x * 128;
    const int m0 = (w >> 1) * 64, n0 = (w & 1) * 64;

    const int kchunk = K / gridDim.z;
    const int koff = blockIdx.z * kchunk;
    outF += (size_t)blockIdx.z * pstride;

    f32x4 acc[4][4];
    for (int i = 0; i < 4; i++)
        for (int j = 0; j < 4; j++)
            acc[i][j] = (f32x4){0.f, 0.f, 0.f, 0.f};

    const int pa0 = 2 * w, pa1 = 2 * w + 1;
    const int srow = lane >> 2, sch = lane & 3;
    const u16* Abase = A + (size_t)tM * K + koff;
    const u16* Bbase = Bt + (size_t)tN * K + koff;
    const size_t r0 = (size_t)(pa0 * 16 + srow) * K + sch * 8;
    const size_t r1 = (size_t)(pa1 * 16 + srow) * K + sch * 8;

    ASYNC16(Abase + r0, lA + pa0 * 512);
    ASYNC16(Abase + r1, lA + pa1 * 512);
    ASYNC16(Bbase + r0, lB + pa0 * 512);
    ASYNC16(Bbase + r1, lB + pa1 * 512);

    const int NT = kchunk / 32;
    for (int kt = 0; kt < NT; kt++) {
        __syncthreads();
        const int cb = (kt & 1) * 4096, nb = 4096 - cb;
        if (kt + 1 < NT) {
            const int k0 = (kt + 1) * 32;
            ASYNC16(Abase + r0 + k0, lA + nb + pa0 * 512);
            ASYNC16(Abase + r1 + k0, lA + nb + pa1 * 512);
            ASYNC16(Bbase + r0 + k0, lB + nb + pa0 * 512);
            ASYNC16(Bbase + r1 + k0, lB + nb + pa1 * 512);
        }
        short8 af[4], bf[4];
        for (int i = 0; i < 4; i++) af[i] = *(const short8*)&lA[cb + (m0 + i * 16 + lane15) * 32 + q * 8];
        for (int j = 0; j < 4; j++) bf[j] = *(const short8*)&lB[cb + (n0 + j * 16 + lane15) * 32 + q * 8];
        for (int i = 0; i < 4; i++)
            for (int j = 0; j < 4; j++)
                acc[i][j] = MFMA16(af[i], bf[j], acc[i][j]);
    }

    if (mode == MODE_F32) {
        for (int i = 0; i < 4; i++) {
            const int rb = tM + m0 + i * 16 + q * 4;
            for (int j = 0; j < 4; j++) {
                const int col = tN + n0 + j * 16 + lane15;
                const float bv = (bias && blockIdx.z == 0) ? bias[col] : 0.f;
                for (int r = 0; r < 4; r++)
                    outF[(size_t)(rb + r) * N + col] = acc[i][j][r] + bv;
            }
        }
        return;
    }

    u16* sC = SM;   // 128 x 136
    __syncthreads();
    if (mode == MODE_GELU) {
        for (int i = 0; i < 4; i++) {
            const int rl0 = m0 + i * 16 + q * 4;
            for (int j = 0; j < 4; j++) {
                const int cl = n0 + j * 16 + lane15;
                const float bv = bias[tN + cl];
                for (int r = 0; r < 4; r++) {
                    float v = acc[i][j][r] + bv;
                    v = 0.5f * v * (1.f + erff(v * 0.70710678118f));
                    sC[(rl0 + r) * 136 + cl] = f2b(v);
                }
            }
        }
        __syncthreads();
        for (int t8 = 0; t8 < 8; t8++) {
            const int rl = t8 * 16 + (tid >> 4), cl = (tid & 15) * 8;
            *(u16x8*)&outB[(size_t)(tM + rl) * N + tN + cl] = *(const u16x8*)&sC[rl * 136 + cl];
        }
    } else {  // MODE_VT
        for (int i = 0; i < 4; i++) {
            const int rl0 = m0 + i * 16 + q * 4;
            for (int j = 0; j < 4; j++) {
                const int cl = n0 + j * 16 + lane15;
                const float bv = bias[tN + cl];
                for (int r = 0; r < 4; r++)
                    sC[cl * 136 + rl0 + r] = f2b(acc[i][j][r] + bv);
            }
        }
        __syncthreads();
        const int bb = tM >> 11, nbase = tM & 2047;
        for (int t8 = 0; t8 < 8; t8++) {
            const int cl = t8 * 16 + (tid >> 4), rl = (tid & 15) * 8;
            const int colg = tN + cl;
            u16* dst = &outB[((size_t)(bb * 16 + (colg >> 6)) * 64 + (colg & 63)) * 2048 + nbase + rl];
            *(u16x8*)dst = *(const u16x8*)&sC[cl * 136 + rl];
        }
    }
}

// ---------------------------------------------------------------------------
// Flash attention, bf16x3 QK^T (Q pre-scaled by 8*log2e -> exp2 softmax)
// grid 1024: bh = blk&31 (XCD-clustered), qb = 31-(blk>>5) heaviest-first
// dbuf K/V; LDS 40KB -> 4 blocks/CU (lP aliases dead Q-staging region);
// row-sum via ones-MFMA; compute skipped on fully-masked tiles.
// ---------------------------------------------------------------------------
__global__ __launch_bounds__(256) void attn_fwd(
    const u16* __restrict__ Qhig, const u16* __restrict__ Qlog,
    const u16* __restrict__ Khig, const u16* __restrict__ Klog,
    const u16* __restrict__ Vtg, u16* __restrict__ Og)
{
    __shared__ u16 lQh[2][2048], lQl[2][2048];        // dead after t=0 frag read
    __shared__ u16 lKh[2][2][1024], lKl[2][2][1024];  // [buf][d-half][32 keys x 32]
    __shared__ u16 lV[2][2048];                       // [buf][64 d x 32 keys]

    const int tid = threadIdx.x, w = tid >> 6, lane = tid & 63;
    const int lane15 = lane & 15, q = lane >> 4;
    const int bh = blockIdx.x & 31;          // same bh -> same XCD (mod 8)
    const int qb = 31 - (blockIdx.x >> 5);   // heaviest q-blocks first
    const int b = bh >> 4, h = bh & 15;

    const size_t xoff = (size_t)b * 2048 * 1024 + h * 64;
    const u16* Qh_ = Qhig + xoff;
    const u16* Ql_ = Qlog + xoff;
    const u16* Kh_ = Khig + xoff;
    const u16* Kl_ = Klog + xoff;
    const u16* Vbh = Vtg + (size_t)bh * 64 * 2048;
    u16* Obh = Og + xoff;

    u16* lP = &lQh[0][0] + w * 640;          // per-wave 16x40, aliases Q staging

    const int srow = lane >> 2, sch = lane & 3;
    const float NEG = -3.0e38f;
    const int qrow0 = qb * 64;
    const int wrow0 = qrow0 + w * 16;        // this wave's first query row
    const int ntiles = 2 * qb + 2;

    short8 ones;
    for (int i = 0; i < 8; i++) ones[i] = (short)0x3F80;   // bf16 1.0 splat

    // prologue: stage Q hi+lo (16 chunks, 4/wave) and K/V tile 0 (12 chunks, 3/wave)
    for (int ii = 0; ii < 4; ii++) {
        const int id = w * 4 + ii;
        const int idq = id & 7, ks = idq >> 2, p = idq & 3;
        const size_t so = (size_t)(qrow0 + p * 16 + srow) * 1024 + ks * 32 + sch * 8;
        if (id < 8) ASYNC16(Qh_ + so, &lQh[ks][p * 512]);
        else        ASYNC16(Ql_ + so, &lQl[ks][p * 512]);
    }
    for (int ii = 0; ii < 3; ii++) {
        const int id = w * 3 + ii;
        if (id < 8) {
            const int sel = id >> 2, idk = id & 3, ks = idk >> 1, hh = idk & 1;
            const size_t so = (size_t)(hh * 16 + srow) * 1024 + ks * 32 + sch * 8;
            if (sel == 0) ASYNC16(Kh_ + so, &lKh[0][ks][hh * 512]);
            else          ASYNC16(Kl_ + so, &lKl[0][ks][hh * 512]);
        } else {
            const int p = id - 8;
            ASYNC16(Vbh + (size_t)(p * 16 + srow) * 2048 + sch * 8, &lV[0][p * 512]);
        }
    }

    f32x4 o[4];
    for (int j = 0; j < 4; j++) o[j] = (f32x4){0.f, 0.f, 0.f, 0.f};
    float mrow[4], lrow[4];
    for (int r = 0; r < 4; r++) { mrow[r] = NEG; lrow[r] = 0.f; }
    short8 aqh0 = {}, aqh1 = {}, aql0 = {}, aql1 = {};

    for (int t = 0; t < ntiles; t++) {
        __syncthreads();   // tile t (+Q at t=0) resident
        const int cur = t & 1, nxt = cur ^ 1;
        if (t == 0) {
            const int o0 = (w * 16 + lane15) * 32 + q * 8;
            aqh0 = *(const short8*)&lQh[0][o0];
            aqh1 = *(const short8*)&lQh[1][o0];
            aql0 = *(const short8*)&lQl[0][o0];
            aql1 = *(const short8*)&lQl[1][o0];
            __syncthreads();   // all waves' Q frags read before any lP write
        }
        if (t + 1 < ntiles) {   // prefetch tile t+1 into other buffer
            const int kk1 = (t + 1) * 32;
            for (int ii = 0; ii < 3; ii++) {
                const int id = w * 3 + ii;
                if (id < 8) {
                    const int sel = id >> 2, idk = id & 3, ks = idk >> 1, hh = idk & 1;
                    const size_t so = (size_t)(kk1 + hh * 16 + srow) * 1024 + ks * 32 + sch * 8;
                    if (sel == 0) ASYNC16(Kh_ + so, &lKh[nxt][ks][hh * 512]);
                    else          ASYNC16(Kl_ + so, &lKl[nxt][ks][hh * 512]);
                } else {
                    const int p = id - 8;
                    ASYNC16(Vbh + (size_t)(p * 16 + srow) * 2048 + kk1 + sch * 8,
                            &lV[nxt][p * 512]);
                }
            }
        }
        const int kk0 = t * 32;
        if (kk0 > wrow0 + 15) continue;   // tile fully masked for this wave (uniform)

        // S = (Qhi+Qlo)(Khi+Klo)^T (lo*lo dropped); logits already * 8*log2e
        f32x4 s[2];
        for (int sub = 0; sub < 2; sub++) {
            const int ko = (sub * 16 + lane15) * 32 + q * 8;
            short8 bkh0 = *(const short8*)&lKh[cur][0][ko];
            short8 bkh1 = *(const short8*)&lKh[cur][1][ko];
            short8 bkl0 = *(const short8*)&lKl[cur][0][ko];
            short8 bkl1 = *(const short8*)&lKl[cur][1][ko];
            f32x4 z = (f32x4){0.f, 0.f, 0.f, 0.f};
            z = MFMA16(aqh0, bkh0, z);
            z = MFMA16(aqh1, bkh1, z);
            z = MFMA16(aqh0, bkl0, z);
            z = MFMA16(aqh1, bkl1, z);
            z = MFMA16(aql0, bkh0, z);
            z = MFMA16(aql1, bkh1, z);
            s[sub] = z;
        }
        // causal mask: only the wave's diagonal tile needs it (uniform check)
        const int rbase = wrow0 + q * 4;
        if (kk0 + 31 > wrow0) {
            for (int sub = 0; sub < 2; sub++)
                for (int r = 0; r < 4; r++) {
                    const int key = kk0 + sub * 16 + lane15;
                    if (key > rbase + r) s[sub][r] = NEG;
                }
        }
        // online softmax max (rows live in 16-lane groups)
        float mx[4];
        for (int r = 0; r < 4; r++) mx[r] = fmaxf(s[0][r], s[1][r]);
        for (int d = 1; d < 16; d <<= 1)
            for (int r = 0; r < 4; r++) mx[r] = fmaxf(mx[r], __shfl_xor(mx[r], d));
        float alpha[4];
        for (int r = 0; r < 4; r++) {
            const float mnew = fmaxf(mrow[r], mx[r]);
            alpha[r] = __builtin_exp2f(mrow[r] - mnew);
            mrow[r] = mnew;
        }
        // P (truncating bf16 pack; numerator & denominator use identical values)
        for (int sub = 0; sub < 2; sub++)
            for (int r = 0; r < 4; r++) {
                const float p = __builtin_exp2f(s[sub][r] - mrow[r]);
                lP[(q * 4 + r) * 40 + sub * 16 + lane15] = f2b_trunc(p);
            }
        short8 ap = *(const short8*)&lP[lane15 * 40 + q * 8];
        // row-sum via ones-MFMA: every lane's C holds the full row sum
        f32x4 zs = (f32x4){0.f, 0.f, 0.f, 0.f};
        zs = MFMA16(ap, ones, zs);
        for (int r = 0; r < 4; r++) lrow[r] = lrow[r] * alpha[r] + zs[r];
        for (int j = 0; j < 4; j++)
            for (int r = 0; r < 4; r++) o[j][r] *= alpha[r];
        // O += P V
        for (int j = 0; j < 4; j++) {
            short8 bv = *(const short8*)&lV[cur][(j * 16 + lane15) * 32 + q * 8];
            o[j] = MFMA16(ap, bv, o[j]);
        }
    }
    // normalize + write
    float inv[4];
    for (int r = 0; r < 4; r++) inv[r] = 1.0f / lrow[r];
    for (int j = 0; j < 4; j++)
        for (int r = 0; r < 4; r++)
            Obh[(size_t)(qrow0 + w * 16 + q * 4 + r) * 1024 + j * 16 + lane15] =
                f2b(o[j][r] * inv[r]);
}

// ---------------------------------------------------------------------------
// y = LN(Xa [+Xb])*g + b + res; res fp32 or bf16; out bf16 and/or fp32
// ---------------------------------------------------------------------------
__global__ __launch_bounds__(256) void ln_res(
    const float* __restrict__ Xa, const float* __restrict__ Xb,
    const float* __restrict__ resF, const u16* __restrict__ resB,
    const float* __restrict__ g, const float* __restrict__ bb,
    u16* __restrict__ outB, float* __restrict__ outF)
{
    const int w = threadIdx.x >> 6, lane = threadIdx.x & 63;
    const int row = blockIdx.x * 4 + w;
    const size_t rowo = (size_t)row * 1024;
    f32x4 v[4];
    float s = 0.f, ss = 0.f;
    for (int i = 0; i < 4; i++) {
        const int c0 = (i * 64 + lane) * 4;
        v[i] = *(const f32x4*)&Xa[rowo + c0];
        if (Xb) {
            f32x4 v2 = *(const f32x4*)&Xb[rowo + c0];
            for (int k = 0; k < 4; k++) v[i][k] += v2[k];
        }
        for (int k = 0; k < 4; k++) { s += v[i][k]; ss += v[i][k] * v[i][k]; }
    }
    for (int d = 1; d < 64; d <<= 1) { s += __shfl_xor(s, d); ss += __shfl_xor(ss, d); }
    const float mu = s * (1.f / 1024.f);
    const float var = ss * (1.f / 1024.f) - mu * mu;
    const float rstd = rsqrtf(var + 1e-5f);
    for (int i = 0; i < 4; i++) {
        const int c0 = (i * 64 + lane) * 4;
        f32x4 gv = *(const f32x4*)&g[c0];
        f32x4 bv = *(const f32x4*)&bb[c0];
        f32x4 rv;
        if (resF) rv = *(const f32x4*)&resF[rowo + c0];
        else {
            u16x4 rb = *(const u16x4*)&resB[rowo + c0];
            for (int k = 0; k < 4; k++) rv[k] = b2f(rb[k]);
        }
        f32x4 ov;
        for (int k = 0; k < 4; k++)
            ov[k] = (v[i][k] - mu) * rstd * gv[k] + bv[k] + rv[k];
        if (outF) *(f32x4*)&outF[rowo + c0] = ov;
        if (outB) {
            u16x4 ob;
            for (int k = 0; k < 4; k++) ob[k] = f2b(ov[k]);
            *(u16x4*)&outB[rowo + c0] = ob;
        }
    }
}

// ---------------------------------------------------------------------------
extern "C" void kernel_launch(void* const* d_in, const int* in_sizes, int n_in,
                              void* d_out, int out_size, void* d_ws, size_t ws_size,
                              hipStream_t stream)
{
    const float* x   = (const float*)d_in[0];
    const float* Wq  = (const float*)d_in[1];  const float* bq  = (const float*)d_in[2];
    const float* Wk  = (const float*)d_in[3];  const float* bk  = (const float*)d_in[4];
    const float* Wv  = (const float*)d_in[5];  const float* bv  = (const float*)d_in[6];
    const float* Wo  = (const float*)d_in[7];  const float* bo  = (const float*)d_in[8];
    const float* g1  = (const float*)d_in[9];  const float* b1  = (const float*)d_in[10];
    const float* W1  = (const float*)d_in[11]; const float* bm1 = (const float*)d_in[12];
    const float* W2  = (const float*)d_in[13]; const float* bm2 = (const float*)d_in[14];
    const float* g2  = (const float*)d_in[15]; const float* b2  = (const float*)d_in[16];

    // workspace (88 MB peak, lifetime-aliased); MB = 1 MiB
    const size_t MB = (size_t)1 << 20;
    char* ws = (char*)d_ws;
    u16* xhi    = (u16*)(ws + 0 * MB);
    u16* xlo    = (u16*)(ws + 8 * MB);
    u16* WqkThi = (u16*)(ws + 16 * MB);
    u16* WqkTlo = (u16*)(ws + 20 * MB);
    u16* WvT    = (u16*)(ws + 24 * MB);
    u16* WoT    = (u16*)(ws + 26 * MB);
    u16* W1T    = (u16*)(ws + 32 * MB);
    u16* W2T    = (u16*)(ws + 40 * MB);
    u16* Qhi    = (u16*)(ws + 48 * MB);
    u16* Qlo    = (u16*)(ws + 56 * MB);
    u16* Khi    = (u16*)(ws + 64 * MB);
    u16* Klo    = (u16*)(ws + 72 * MB);
    u16* Vtb    = (u16*)(ws + 80 * MB);
    u16* aout   = (u16*)(ws + 16 * MB);
    float* O1   = (float*)(ws + 48 * MB);
    float* O2   = (float*)(ws + 64 * MB);
    u16* x1b    = (u16*)(ws + 80 * MB);
    u16* Hb     = (u16*)(ws + 0 * MB);
    float* H2a  = (float*)(ws + 48 * MB);
    float* H2b  = (float*)(ws + 64 * MB);

    split_f32<<<4096, 256, 0, stream>>>(x, xhi, xlo);
    transpose_split_f32<<<dim3(32, 32, 2), 256, 0, stream>>>(
        Wq, WqkThi, WqkTlo,
        Wk, WqkThi + 1024 * 1024, WqkTlo + 1024 * 1024, 1024, 1024);
    transpose_f32_bf16<<<dim3(32, 32, 2), 256, 0, stream>>>(Wv, WvT, Wo, WoT, 1024, 1024);
    transpose_f32_bf16<<<dim3(128, 32), 256, 0, stream>>>(W1, W1T, nullptr, nullptr, 1024, 4096);
    transpose_f32_bf16<<<dim3(32, 128), 256, 0, stream>>>(W2, W2T, nullptr, nullptr, 4096, 1024);

    gemm_qk_x3<<<dim3(16, 32), 256, 0, stream>>>(xhi, xlo, WqkThi, WqkTlo, bq, bk,
                                                 Qhi, Qlo, Khi, Klo);
    gemm_bt<<<dim3(8, 32), 256, 0, stream>>>(xhi, WvT, bv, 4096, 1024, 1024,
                                             MODE_VT, nullptr, Vtb, 0);

    attn_fwd<<<dim3(1024), 256, 0, stream>>>(Qhi, Qlo, Khi, Klo, Vtb, aout);

    gemm_bt<<<dim3(8, 32, 2), 256, 0, stream>>>(aout, WoT, bo, 4096, 1024, 1024,
                                                MODE_F32, O1, nullptr, (size_t)16 * MB / 4);
    ln_res<<<1024, 256, 0, stream>>>(O1, O2, x, nullptr, g1, b1, x1b, nullptr);

    gemm_bt<<<dim3(32, 32), 256, 0, stream>>>(x1b, W1T, bm1, 4096, 4096, 1024,
                                              MODE_GELU, nullptr, Hb, 0);
    gemm_bt<<<dim3(8, 32, 2), 256, 0, stream>>>(Hb, W2T, bm2, 4096, 1024, 4096,
                                                MODE_F32, H2a, nullptr, (size_t)16 * MB / 4);
    ln_res<<<1024, 256, 0, stream>>>(H2a, H2b, nullptr, x1b, g2, b2, nullptr, (float*)d_out);
}

// Round 9
// 446.028 us; speedup vs baseline: 3.4096x; 1.0582x over previous
//
#include <hip/hip_runtime.h>
#include <stdint.h>

typedef unsigned short u16;
typedef short short8 __attribute__((ext_vector_type(8)));
typedef float f32x4 __attribute__((ext_vector_type(4)));
typedef u16 u16x4 __attribute__((ext_vector_type(4)));
typedef u16 u16x8 __attribute__((ext_vector_type(8)));

#define MODE_F32  0
#define MODE_GELU 2
#define MODE_VT   4

// 8 (bug-faithful sqrt(hd) scale) * log2(e): softmax runs in exp2 domain
#define QSCALE 11.5415603271f

__device__ __forceinline__ float b2f(u16 v) {
    union { uint32_t u; float f; } x; x.u = ((uint32_t)v) << 16; return x.f;
}
__device__ __forceinline__ u16 f2b(float f) {
    union { float f; uint32_t u; } x; x.f = f;
    uint32_t u = x.u;
    return (u16)((u + 0x7FFFu + ((u >> 16) & 1u)) >> 16);   // RNE
}
__device__ __forceinline__ u16 f2b_trunc(float f) {        // cheap: P only
    union { float f; uint32_t u; } x; x.f = f;
    return (u16)(x.u >> 16);
}

// async global->LDS, 16B per lane; LDS dest is wave-uniform base + lane*16
#define ASYNC16(gp, lp)                                                        \
    __builtin_amdgcn_global_load_lds(                                          \
        (const __attribute__((address_space(1))) uint32_t*)(const void*)(gp),  \
        (__attribute__((address_space(3))) uint32_t*)(void*)(lp), 16, 0, 0)

#define MFMA16(a, b, c) __builtin_amdgcn_mfma_f32_16x16x32_bf16((a), (b), (c), 0, 0, 0)

// ---------------------------------------------------------------------------
// fp32 -> (hi, lo) bf16 split
// ---------------------------------------------------------------------------
__global__ __launch_bounds__(256) void split_f32(
    const float* __restrict__ in, u16* __restrict__ hi, u16* __restrict__ lo)
{
    const int i = (blockIdx.x * 256 + threadIdx.x) * 4;
    f32x4 v = *(const f32x4*)&in[i];
    u16x4 h, l;
    for (int k = 0; k < 4; k++) {
        h[k] = f2b(v[k]);
        l[k] = f2b(v[k] - b2f(h[k]));
    }
    *(u16x4*)&hi[i] = h;
    *(u16x4*)&lo[i] = l;
}

// fp32 [rows,cols] -> bf16 [cols,rows] transpose+cast; z picks (inA,outA)/(inB,outB)
__global__ __launch_bounds__(256) void transpose_f32_bf16(
    const float* __restrict__ inA, u16* __restrict__ outA,
    const float* __restrict__ inB, u16* __restrict__ outB, int rows, int cols)
{
    const float* in = blockIdx.z ? inB : inA;
    u16* out = blockIdx.z ? outB : outA;
    __shared__ float t[32][33];
    const int r0 = blockIdx.y * 32, c0 = blockIdx.x * 32;
    const int tr = threadIdx.x >> 3, tc = (threadIdx.x & 7) * 4;
    f32x4 v = *(const f32x4*)&in[(size_t)(r0 + tr) * cols + c0 + tc];
    for (int i = 0; i < 4; i++) t[tr][tc + i] = v[i];
    __syncthreads();
    u16x4 ov;
    for (int i = 0; i < 4; i++) ov[i] = f2b(t[tc + i][tr]);
    *(u16x4*)&out[(size_t)(c0 + tr) * rows + r0 + tc] = ov;
}

// fp32 [rows,cols] -> bf16 hi/lo [cols,rows] transpose+split; z picks A/B set
__global__ __launch_bounds__(256) void transpose_split_f32(
    const float* __restrict__ inA, u16* __restrict__ hiA, u16* __restrict__ loA,
    const float* __restrict__ inB, u16* __restrict__ hiB, u16* __restrict__ loB,
    int rows, int cols)
{
    const float* in = blockIdx.z ? inB : inA;
    u16* hi = blockIdx.z ? hiB : hiA;
    u16* lo = blockIdx.z ? loB : loA;
    __shared__ float t[32][33];
    const int r0 = blockIdx.y * 32, c0 = blockIdx.x * 32;
    const int tr = threadIdx.x >> 3, tc = (threadIdx.x & 7) * 4;
    f32x4 v = *(const f32x4*)&in[(size_t)(r0 + tr) * cols + c0 + tc];
    for (int i = 0; i < 4; i++) t[tr][tc + i] = v[i];
    __syncthreads();
    u16x4 hv, lv;
    for (int i = 0; i < 4; i++) {
        const float f = t[tc + i][tr];
        hv[i] = f2b(f);
        lv[i] = f2b(f - b2f(hv[i]));
    }
    const size_t o = (size_t)(c0 + tr) * rows + r0 + tc;
    *(u16x4*)&hi[o] = hv;
    *(u16x4*)&lo[o] = lv;
}

// ---------------------------------------------------------------------------
// QK projection, bf16x3, dbuf, 8 waves/block (wave-tile 32x64, acc 2x4)
// Q output pre-scaled by QSCALE (8*log2e) for the exp2-domain softmax.
// ---------------------------------------------------------------------------
__global__ __launch_bounds__(512) void gemm_qk_x3(
    const u16* __restrict__ Ahi, const u16* __restrict__ Alo,
    const u16* __restrict__ Bhi, const u16* __restrict__ Blo,
    const float* __restrict__ bq, const float* __restrict__ bk,
    u16* __restrict__ Qhi, u16* __restrict__ Qlo,
    u16* __restrict__ Khi, u16* __restrict__ Klo)
{
    const int K = 1024;
    __shared__ __align__(16) u16 SM[32768];   // 64 KB: 4 operands x dbuf
    u16* lAh = SM;          u16* lAl = SM + 8192;
    u16* lBh = SM + 16384;  u16* lBl = SM + 24576;

    const int tid = threadIdx.x;
    const int w = tid >> 6, lane = tid & 63;
    const int lane15 = lane & 15, q = lane >> 4;
    const int tM = blockIdx.y * 128, tN = blockIdx.x * 128;
    const int m0 = (w >> 1) * 32, n0 = (w & 1) * 64;

    f32x4 acc[2][4];
    for (int i = 0; i < 2; i++)
        for (int j = 0; j < 4; j++)
            acc[i][j] = (f32x4){0.f, 0.f, 0.f, 0.f};

    const int srow = lane >> 2, sch = lane & 3;
    const u16* Ah = Ahi + (size_t)tM * K;
    const u16* Al = Alo + (size_t)tM * K;
    const u16* Bh = Bhi + (size_t)tN * K;
    const u16* Bl = Blo + (size_t)tN * K;
    // 32 staging chunks (4 operands x 8), 4 per wave: id = w*4+ii
    // id>>3 selects operand (Ah,Al,Bh,Bl), id&7 selects 16-row chunk
    const size_t roff = (size_t)((w * 4) & 7) * 16 * K;   // base for this wave's chunk group

    #define STAGE_QK(buf_off, k0)                                              \
        for (int ii = 0; ii < 4; ii++) {                                       \
            const int id = w * 4 + ii, op = id >> 3, ch = id & 7;              \
            const u16* src = op == 0 ? Ah : op == 1 ? Al : op == 2 ? Bh : Bl;  \
            u16* dst = op == 0 ? lAh : op == 1 ? lAl : op == 2 ? lBh : lBl;    \
            ASYNC16(src + (size_t)(ch * 16 + srow) * K + (k0) + sch * 8,       \
                    dst + (buf_off) + ch * 512);                               \
        }

    STAGE_QK(0, 0)

    const int NT = K / 32;
    for (int kt = 0; kt < NT; kt++) {
        __syncthreads();
        const int cb = (kt & 1) * 4096, nb = 4096 - cb;
        if (kt + 1 < NT) {
            const int k0 = (kt + 1) * 32;
            STAGE_QK(nb, k0)
        }
        short8 afh[2], afl[2], bfh[4], bfl[4];
        for (int i = 0; i < 2; i++) {
            const int o = cb + (m0 + i * 16 + lane15) * 32 + q * 8;
            afh[i] = *(const short8*)&lAh[o];
            afl[i] = *(const short8*)&lAl[o];
        }
        for (int j = 0; j < 4; j++) {
            const int o = cb + (n0 + j * 16 + lane15) * 32 + q * 8;
            bfh[j] = *(const short8*)&lBh[o];
            bfl[j] = *(const short8*)&lBl[o];
        }
        for (int i = 0; i < 2; i++)
            for (int j = 0; j < 4; j++) {
                acc[i][j] = MFMA16(afh[i], bfh[j], acc[i][j]);
                acc[i][j] = MFMA16(afh[i], bfl[j], acc[i][j]);
                acc[i][j] = MFMA16(afl[i], bfh[j], acc[i][j]);
            }
    }

    // epilogue: Q (tN<1024, scaled) or K; hi+lo passes through LDS, vec8 stores
    const bool isQ = (tN < 1024);
    u16* dhi = isQ ? Qhi : Khi;
    u16* dlo = isQ ? Qlo : Klo;
    const int cN = isQ ? tN : (tN - 1024);
    const float scl = isQ ? QSCALE : 1.0f;
    u16* sC = SM;   // 128 x 136
    for (int pass = 0; pass < 2; pass++) {
        __syncthreads();
        for (int i = 0; i < 2; i++) {
            const int rl0 = m0 + i * 16 + q * 4;
            for (int j = 0; j < 4; j++) {
                const int cl = n0 + j * 16 + lane15;
                const float bv = isQ ? bq[cN + cl] : bk[cN + cl];
                for (int r = 0; r < 4; r++) {
                    const float v = (acc[i][j][r] + bv) * scl;
                    const u16 hv = f2b(v);
                    sC[(rl0 + r) * 136 + cl] = pass == 0 ? hv : f2b(v - b2f(hv));
                }
            }
        }
        __syncthreads();
        u16* dst = pass == 0 ? dhi : dlo;
        for (int t8 = 0; t8 < 4; t8++) {
            const int rl = t8 * 32 + (tid >> 4), cl = (tid & 15) * 8;
            *(u16x8*)&dst[(size_t)(tM + rl) * 1024 + cN + cl] = *(const u16x8*)&sC[rl * 136 + cl];
        }
    }
}

// ---------------------------------------------------------------------------
// C = A[M,K] * Bt[N,K]^T + bias; dbuf; 8 waves/block (wave-tile 32x64);
// optional split-K via gridDim.z
// ---------------------------------------------------------------------------
__global__ __launch_bounds__(512) void gemm_bt(
    const u16* __restrict__ A, const u16* __restrict__ Bt, const float* __restrict__ bias,
    int M, int N, int K, int mode,
    float* __restrict__ outF, u16* __restrict__ outB, size_t pstride)
{
    __shared__ __align__(16) u16 SM[17408];
    u16* lA = SM;
    u16* lB = SM + 8192;

    const int tid = threadIdx.x;
    const int w = tid >> 6, lane = tid & 63;
    const int lane15 = lane & 15, q = lane >> 4;
    const int tM = blockIdx.y * 128, tN = blockIdx.x * 128;
    const int m0 = (w >> 1) * 32, n0 = (w & 1) * 64;

    const int kchunk = K / gridDim.z;
    const int koff = blockIdx.z * kchunk;
    outF += (size_t)blockIdx.z * pstride;

    f32x4 acc[2][4];
    for (int i = 0; i < 2; i++)
        for (int j = 0; j < 4; j++)
            acc[i][j] = (f32x4){0.f, 0.f, 0.f, 0.f};

    const int srow = lane >> 2, sch = lane & 3;
    const u16* Abase = A + (size_t)tM * K + koff;
    const u16* Bbase = Bt + (size_t)tN * K + koff;
    // 16 staging chunks (A 0..7, B 8..15), 2 per wave
    #define STAGE_BT(buf_off, k0)                                              \
        for (int ii = 0; ii < 2; ii++) {                                       \
            const int id = w * 2 + ii;                                         \
            const u16* src = id < 8 ? Abase : Bbase;                           \
            u16* dst = id < 8 ? lA : lB;                                       \
            const int ch = id & 7;                                             \
            ASYNC16(src + (size_t)(ch * 16 + srow) * K + (k0) + sch * 8,       \
                    dst + (buf_off) + ch * 512);                               \
        }

    STAGE_BT(0, 0)

    const int NT = kchunk / 32;
    for (int kt = 0; kt < NT; kt++) {
        __syncthreads();
        const int cb = (kt & 1) * 4096, nb = 4096 - cb;
        if (kt + 1 < NT) {
            const int k0 = (kt + 1) * 32;
            STAGE_BT(nb, k0)
        }
        short8 af[2], bf[4];
        for (int i = 0; i < 2; i++) af[i] = *(const short8*)&lA[cb + (m0 + i * 16 + lane15) * 32 + q * 8];
        for (int j = 0; j < 4; j++) bf[j] = *(const short8*)&lB[cb + (n0 + j * 16 + lane15) * 32 + q * 8];
        for (int i = 0; i < 2; i++)
            for (int j = 0; j < 4; j++)
                acc[i][j] = MFMA16(af[i], bf[j], acc[i][j]);
    }

    if (mode == MODE_F32) {
        for (int i = 0; i < 2; i++) {
            const int rb = tM + m0 + i * 16 + q * 4;
            for (int j = 0; j < 4; j++) {
                const int col = tN + n0 + j * 16 + lane15;
                const float bv = (bias && blockIdx.z == 0) ? bias[col] : 0.f;
                for (int r = 0; r < 4; r++)
                    outF[(size_t)(rb + r) * N + col] = acc[i][j][r] + bv;
            }
        }
        return;
    }

    u16* sC = SM;   // 128 x 136
    __syncthreads();
    if (mode == MODE_GELU) {
        for (int i = 0; i < 2; i++) {
            const int rl0 = m0 + i * 16 + q * 4;
            for (int j = 0; j < 4; j++) {
                const int cl = n0 + j * 16 + lane15;
                const float bv = bias[tN + cl];
                for (int r = 0; r < 4; r++) {
                    float v = acc[i][j][r] + bv;
                    v = 0.5f * v * (1.f + erff(v * 0.70710678118f));
                    sC[(rl0 + r) * 136 + cl] = f2b(v);
                }
            }
        }
        __syncthreads();
        for (int t8 = 0; t8 < 4; t8++) {
            const int rl = t8 * 32 + (tid >> 4), cl = (tid & 15) * 8;
            *(u16x8*)&outB[(size_t)(tM + rl) * N + tN + cl] = *(const u16x8*)&sC[rl * 136 + cl];
        }
    } else {  // MODE_VT
        for (int i = 0; i < 2; i++) {
            const int rl0 = m0 + i * 16 + q * 4;
            for (int j = 0; j < 4; j++) {
                const int cl = n0 + j * 16 + lane15;
                const float bv = bias[tN + cl];
                for (int r = 0; r < 4; r++)
                    sC[cl * 136 + rl0 + r] = f2b(acc[i][j][r] + bv);
            }
        }
        __syncthreads();
        const int bb = tM >> 11, nbase = tM & 2047;
        for (int t8 = 0; t8 < 4; t8++) {
            const int cl = t8 * 32 + (tid >> 4), rl = (tid & 15) * 8;
            const int colg = tN + cl;
            u16* dst = &outB[((size_t)(bb * 16 + (colg >> 6)) * 64 + (colg & 63)) * 2048 + nbase + rl];
            *(u16x8*)dst = *(const u16x8*)&sC[cl * 136 + rl];
        }
    }
}

// ---------------------------------------------------------------------------
// Flash attention, bf16x3 QK^T (Q pre-scaled by 8*log2e -> exp2 softmax)
// grid 1024: bh = blk&31 (XCD-clustered); qb interleaved {31,0,30,1,...} so
// each CU's resident set is work-balanced. dbuf K/V; row-sum via ones-MFMA.
// ---------------------------------------------------------------------------
__global__ __launch_bounds__(256) void attn_fwd(
    const u16* __restrict__ Qhig, const u16* __restrict__ Qlog,
    const u16* __restrict__ Khig, const u16* __restrict__ Klog,
    const u16* __restrict__ Vtg, u16* __restrict__ Og)
{
    __shared__ u16 lQh[2][2048], lQl[2][2048];        // dead after t=0 frag read
    __shared__ u16 lKh[2][2][1024], lKl[2][2][1024];  // [buf][d-half][32 keys x 32]
    __shared__ u16 lV[2][2048];                       // [buf][64 d x 32 keys]

    const int tid = threadIdx.x, w = tid >> 6, lane = tid & 63;
    const int lane15 = lane & 15, q = lane >> 4;
    const int bh = blockIdx.x & 31;          // same bh -> same XCD (mod 8)
    const int u = blockIdx.x >> 5;
    const int qb = (u & 1) ? (u >> 1) : (31 - (u >> 1));   // balanced interleave
    const int b = bh >> 4, h = bh & 15;

    const size_t xoff = (size_t)b * 2048 * 1024 + h * 64;
    const u16* Qh_ = Qhig + xoff;
    const u16* Ql_ = Qlog + xoff;
    const u16* Kh_ = Khig + xoff;
    const u16* Kl_ = Klog + xoff;
    const u16* Vbh = Vtg + (size_t)bh * 64 * 2048;
    u16* Obh = Og + xoff;

    u16* lP = &lQh[0][0] + w * 640;          // per-wave 16x40, aliases Q staging

    const int srow = lane >> 2, sch = lane & 3;
    const float NEG = -3.0e38f;
    const int qrow0 = qb * 64;
    const int wrow0 = qrow0 + w * 16;        // this wave's first query row
    const int ntiles = 2 * qb + 2;

    short8 ones;
    for (int i = 0; i < 8; i++) ones[i] = (short)0x3F80;   // bf16 1.0 splat

    // prologue: stage Q hi+lo (16 chunks, 4/wave) and K/V tile 0 (12 chunks, 3/wave)
    for (int ii = 0; ii < 4; ii++) {
        const int id = w * 4 + ii;
        const int idq = id & 7, ks = idq >> 2, p = idq & 3;
        const size_t so = (size_t)(qrow0 + p * 16 + srow) * 1024 + ks * 32 + sch * 8;
        if (id < 8) ASYNC16(Qh_ + so, &lQh[ks][p * 512]);
        else        ASYNC16(Ql_ + so, &lQl[ks][p * 512]);
    }
    for (int ii = 0; ii < 3; ii++) {
        const int id = w * 3 + ii;
        if (id < 8) {
            const int sel = id >> 2, idk = id & 3, ks = idk >> 1, hh = idk & 1;
            const size_t so = (size_t)(hh * 16 + srow) * 1024 + ks * 32 + sch * 8;
            if (sel == 0) ASYNC16(Kh_ + so, &lKh[0][ks][hh * 512]);
            else          ASYNC16(Kl_ + so, &lKl[0][ks][hh * 512]);
        } else {
            const int p = id - 8;
            ASYNC16(Vbh + (size_t)(p * 16 + srow) * 2048 + sch * 8, &lV[0][p * 512]);
        }
    }

    f32x4 o[4];
    for (int j = 0; j < 4; j++) o[j] = (f32x4){0.f, 0.f, 0.f, 0.f};
    float mrow[4], lrow[4];
    for (int r = 0; r < 4; r++) { mrow[r] = NEG; lrow[r] = 0.f; }
    short8 aqh0 = {}, aqh1 = {}, aql0 = {}, aql1 = {};

    for (int t = 0; t < ntiles; t++) {
        __syncthreads();   // tile t (+Q at t=0) resident
        const int cur = t & 1, nxt = cur ^ 1;
        if (t == 0) {
            const int o0 = (w * 16 + lane15) * 32 + q * 8;
            aqh0 = *(const short8*)&lQh[0][o0];
            aqh1 = *(const short8*)&lQh[1][o0];
            aql0 = *(const short8*)&lQl[0][o0];
            aql1 = *(const short8*)&lQl[1][o0];
            __syncthreads();   // all waves' Q frags read before any lP write
        }
        if (t + 1 < ntiles) {   // prefetch tile t+1 into other buffer
            const int kk1 = (t + 1) * 32;
            for (int ii = 0; ii < 3; ii++) {
                const int id = w * 3 + ii;
                if (id < 8) {
                    const int sel = id >> 2, idk = id & 3, ks = idk >> 1, hh = idk & 1;
                    const size_t so = (size_t)(kk1 + hh * 16 + srow) * 1024 + ks * 32 + sch * 8;
                    if (sel == 0) ASYNC16(Kh_ + so, &lKh[nxt][ks][hh * 512]);
                    else          ASYNC16(Kl_ + so, &lKl[nxt][ks][hh * 512]);
                } else {
                    const int p = id - 8;
                    ASYNC16(Vbh + (size_t)(p * 16 + srow) * 2048 + kk1 + sch * 8,
                            &lV[nxt][p * 512]);
                }
            }
        }
        const int kk0 = t * 32;
        if (kk0 > wrow0 + 15) continue;   // tile fully masked for this wave (uniform)

        // S = (Qhi+Qlo)(Khi+Klo)^T (lo*lo dropped); logits already * 8*log2e
        f32x4 s[2];
        for (int sub = 0; sub < 2; sub++) {
            const int ko = (sub * 16 + lane15) * 32 + q * 8;
            short8 bkh0 = *(const short8*)&lKh[cur][0][ko];
            short8 bkh1 = *(const short8*)&lKh[cur][1][ko];
            short8 bkl0 = *(const short8*)&lKl[cur][0][ko];
            short8 bkl1 = *(const short8*)&lKl[cur][1][ko];
            f32x4 z = (f32x4){0.f, 0.f, 0.f, 0.f};
            z = MFMA16(aqh0, bkh0, z);
            z = MFMA16(aqh1, bkh1, z);
            z = MFMA16(aqh0, bkl0, z);
            z = MFMA16(aqh1, bkl1, z);
            z = MFMA16(aql0, bkh0, z);
            z = MFMA16(aql1, bkh1, z);
            s[sub] = z;
        }
        // causal mask: only the wave's diagonal tile needs it (uniform check)
        const int rbase = wrow0 + q * 4;
        if (kk0 + 31 > wrow0) {
            for (int sub = 0; sub < 2; sub++)
                for (int r = 0; r < 4; r++) {
                    const int key = kk0 + sub * 16 + lane15;
                    if (key > rbase + r) s[sub][r] = NEG;
                }
        }
        // online softmax max (rows live in 16-lane groups)
        float mx[4];
        for (int r = 0; r < 4; r++) mx[r] = fmaxf(s[0][r], s[1][r]);
        for (int d = 1; d < 16; d <<= 1)
            for (int r = 0; r < 4; r++) mx[r] = fmaxf(mx[r], __shfl_xor(mx[r], d));
        float alpha[4];
        for (int r = 0; r < 4; r++) {
            const float mnew = fmaxf(mrow[r], mx[r]);
            alpha[r] = __builtin_exp2f(mrow[r] - mnew);
            mrow[r] = mnew;
        }
        // P (truncating bf16 pack; numerator & denominator use identical values)
        for (int sub = 0; sub < 2; sub++)
            for (int r = 0; r < 4; r++) {
                const float p = __builtin_exp2f(s[sub][r] - mrow[r]);
                lP[(q * 4 + r) * 40 + sub * 16 + lane15] = f2b_trunc(p);
            }
        short8 ap = *(const short8*)&lP[lane15 * 40 + q * 8];
        // row-sum via ones-MFMA: every lane's C holds the full row sum
        f32x4 zs = (f32x4){0.f, 0.f, 0.f, 0.f};
        zs = MFMA16(ap, ones, zs);
        for (int r = 0; r < 4; r++) lrow[r] = lrow[r] * alpha[r] + zs[r];
        for (int j = 0; j < 4; j++)
            for (int r = 0; r < 4; r++) o[j][r] *= alpha[r];
        // O += P V
        for (int j = 0; j < 4; j++) {
            short8 bv = *(const short8*)&lV[cur][(j * 16 + lane15) * 32 + q * 8];
            o[j] = MFMA16(ap, bv, o[j]);
        }
    }
    // normalize + write
    float inv[4];
    for (int r = 0; r < 4; r++) inv[r] = 1.0f / lrow[r];
    for (int j = 0; j < 4; j++)
        for (int r = 0; r < 4; r++)
            Obh[(size_t)(qrow0 + w * 16 + q * 4 + r) * 1024 + j * 16 + lane15] =
                f2b(o[j][r] * inv[r]);
}

// ---------------------------------------------------------------------------
// y = LN(Xa [+Xb])*g + b + res; res fp32 or bf16; out bf16 and/or fp32
// ---------------------------------------------------------------------------
__global__ __launch_bounds__(256) void ln_res(
    const float* __restrict__ Xa, const float* __restrict__ Xb,
    const float* __restrict__ resF, const u16* __restrict__ resB,
    const float* __restrict__ g, const float* __restrict__ bb,
    u16* __restrict__ outB, float* __restrict__ outF)
{
    const int w = threadIdx.x >> 6, lane = threadIdx.x & 63;
    const int row = blockIdx.x * 4 + w;
    const size_t rowo = (size_t)row * 1024;
    f32x4 v[4];
    float s = 0.f, ss = 0.f;
    for (int i = 0; i < 4; i++) {
        const int c0 = (i * 64 + lane) * 4;
        v[i] = *(const f32x4*)&Xa[rowo + c0];
        if (Xb) {
            f32x4 v2 = *(const f32x4*)&Xb[rowo + c0];
            for (int k = 0; k < 4; k++) v[i][k] += v2[k];
        }
        for (int k = 0; k < 4; k++) { s += v[i][k]; ss += v[i][k] * v[i][k]; }
    }
    for (int d = 1; d < 64; d <<= 1) { s += __shfl_xor(s, d); ss += __shfl_xor(ss, d); }
    const float mu = s * (1.f / 1024.f);
    const float var = ss * (1.f / 1024.f) - mu * mu;
    const float rstd = rsqrtf(var + 1e-5f);
    for (int i = 0; i < 4; i++) {
        const int c0 = (i * 64 + lane) * 4;
        f32x4 gv = *(const f32x4*)&g[c0];
        f32x4 bv = *(const f32x4*)&bb[c0];
        f32x4 rv;
        if (resF) rv = *(const f32x4*)&resF[rowo + c0];
        else {
            u16x4 rb = *(const u16x4*)&resB[rowo + c0];
            for (int k = 0; k < 4; k++) rv[k] = b2f(rb[k]);
        }
        f32x4 ov;
        for (int k = 0; k < 4; k++)
            ov[k] = (v[i][k] - mu) * rstd * gv[k] + bv[k] + rv[k];
        if (outF) *(f32x4*)&outF[rowo + c0] = ov;
        if (outB) {
            u16x4 ob;
            for (int k = 0; k < 4; k++) ob[k] = f2b(ov[k]);
            *(u16x4*)&outB[rowo + c0] = ob;
        }
    }
}

// ---------------------------------------------------------------------------
extern "C" void kernel_launch(void* const* d_in, const int* in_sizes, int n_in,
                              void* d_out, int out_size, void* d_ws, size_t ws_size,
                              hipStream_t stream)
{
    const float* x   = (const float*)d_in[0];
    const float* Wq  = (const float*)d_in[1];  const float* bq  = (const float*)d_in[2];
    const float* Wk  = (const float*)d_in[3];  const float* bk  = (const float*)d_in[4];
    const float* Wv  = (const float*)d_in[5];  const float* bv  = (const float*)d_in[6];
    const float* Wo  = (const float*)d_in[7];  const float* bo  = (const float*)d_in[8];
    const float* g1  = (const float*)d_in[9];  const float* b1  = (const float*)d_in[10];
    const float* W1  = (const float*)d_in[11]; const float* bm1 = (const float*)d_in[12];
    const float* W2  = (const float*)d_in[13]; const float* bm2 = (const float*)d_in[14];
    const float* g2  = (const float*)d_in[15]; const float* b2  = (const float*)d_in[16];

    // workspace (88 MB peak, lifetime-aliased); MB = 1 MiB
    const size_t MB = (size_t)1 << 20;
    char* ws = (char*)d_ws;
    u16* xhi    = (u16*)(ws + 0 * MB);
    u16* xlo    = (u16*)(ws + 8 * MB);
    u16* WqkThi = (u16*)(ws + 16 * MB);
    u16* WqkTlo = (u16*)(ws + 20 * MB);
    u16* WvT    = (u16*)(ws + 24 * MB);
    u16* WoT    = (u16*)(ws + 26 * MB);
    u16* W1T    = (u16*)(ws + 32 * MB);
    u16* W2T    = (u16*)(ws + 40 * MB);
    u16* Qhi    = (u16*)(ws + 48 * MB);
    u16* Qlo    = (u16*)(ws + 56 * MB);
    u16* Khi    = (u16*)(ws + 64 * MB);
    u16* Klo    = (u16*)(ws + 72 * MB);
    u16* Vtb    = (u16*)(ws + 80 * MB);
    u16* aout   = (u16*)(ws + 16 * MB);
    float* O1   = (float*)(ws + 48 * MB);
    float* O2   = (float*)(ws + 64 * MB);
    u16* x1b    = (u16*)(ws + 80 * MB);
    u16* Hb     = (u16*)(ws + 0 * MB);
    float* H2a  = (float*)(ws + 48 * MB);
    float* H2b  = (float*)(ws + 64 * MB);

    split_f32<<<4096, 256, 0, stream>>>(x, xhi, xlo);
    transpose_split_f32<<<dim3(32, 32, 2), 256, 0, stream>>>(
        Wq, WqkThi, WqkTlo,
        Wk, WqkThi + 1024 * 1024, WqkTlo + 1024 * 1024, 1024, 1024);
    transpose_f32_bf16<<<dim3(32, 32, 2), 256, 0, stream>>>(Wv, WvT, Wo, WoT, 1024, 1024);
    transpose_f32_bf16<<<dim3(128, 32), 256, 0, stream>>>(W1, W1T, nullptr, nullptr, 1024, 4096);
    transpose_f32_bf16<<<dim3(32, 128), 256, 0, stream>>>(W2, W2T, nullptr, nullptr, 4096, 1024);

    gemm_qk_x3<<<dim3(16, 32), 512, 0, stream>>>(xhi, xlo, WqkThi, WqkTlo, bq, bk,
                                                 Qhi, Qlo, Khi, Klo);
    gemm_bt<<<dim3(8, 32), 512, 0, stream>>>(xhi, WvT, bv, 4096, 1024, 1024,
                                             MODE_VT, nullptr, Vtb, 0);

    attn_fwd<<<dim3(1024), 256, 0, stream>>>(Qhi, Qlo, Khi, Klo, Vtb, aout);

    gemm_bt<<<dim3(8, 32, 2), 512, 0, stream>>>(aout, WoT, bo, 4096, 1024, 1024,
                                                MODE_F32, O1, nullptr, (size_t)16 * MB / 4);
    ln_res<<<1024, 256, 0, stream>>>(O1, O2, x, nullptr, g1, b1, x1b, nullptr);

    gemm_bt<<<dim3(32, 32), 512, 0, stream>>>(x1b, W1T, bm1, 4096, 4096, 1024,
                                              MODE_GELU, nullptr, Hb, 0);
    gemm_bt<<<dim3(8, 32, 2), 512, 0, stream>>>(Hb, W2T, bm2, 4096, 1024, 4096,
                                                MODE_F32, H2a, nullptr, (size_t)16 * MB / 4);
    ln_res<<<1024, 256, 0, stream>>>(H2a, H2b, nullptr, x1b, g2, b2, nullptr, (float*)d_out);
}